// Round 2
// baseline (7819.358 us; speedup 1.0000x reference)
//
#include <hip/hip_runtime.h>
#include <math.h>

// Shapes (fixed by the problem)
#define B_  16
#define C_  32
#define T_  62
#define V_  19
#define D_  128
#define HD_ 256
#define H_  8
#define DH_ 16            // D_/H_
#define ROWS 18848        // B*T*V == B*V*T
#define BT_ 992           // B*T
#define BV_ 304           // B*V

// ---------------------------------------------------------------------------
// pose [B,C,T,V] -> p [B,T,V,C]
__global__ void transpose_kernel(const float* __restrict__ pose, float* __restrict__ p) {
    int idx = blockIdx.x * 256 + threadIdx.x;
    if (idx >= B_ * T_ * V_ * C_) return;
    int c = idx & 31;
    int rest = idx >> 5;          // b*T*V + t*V + v
    int v = rest % V_;
    int rest2 = rest / V_;
    int t = rest2 % T_;
    int b = rest2 / T_;
    p[idx] = pose[((size_t)((b * C_ + c) * T_ + t)) * V_ + v];
}

// ---------------------------------------------------------------------------
// Generic row-parallel linear: out[r,n] = act( b[n] + sum_k in[r,k]*W[n,k] )
// one block per row, N threads.
template<int K, int N, int ACT>
__global__ __launch_bounds__(N) void linear_kernel(
        const float* __restrict__ in, const float* __restrict__ W,
        const float* __restrict__ bias, float* __restrict__ out, int R) {
    __shared__ float row[K];
    int r = blockIdx.x;
    if (r >= R) return;
    const float* inr = in + (size_t)r * K;
    for (int k = threadIdx.x; k < K; k += N) row[k] = inr[k];
    __syncthreads();
    int n = threadIdx.x;
    float acc = bias ? bias[n] : 0.f;
    const float4* w4 = reinterpret_cast<const float4*>(W + (size_t)n * K);
    #pragma unroll 8
    for (int k4 = 0; k4 < K / 4; ++k4) {
        float4 w = w4[k4];
        acc += row[4 * k4 + 0] * w.x + row[4 * k4 + 1] * w.y
             + row[4 * k4 + 2] * w.z + row[4 * k4 + 3] * w.w;
    }
    if (ACT == 1) acc = fmaxf(acc, 0.f);
    if (ACT == 2) acc = acc >= 0.f ? acc : 0.01f * acc;
    out[(size_t)r * N + n] = acc;
}

// ---------------------------------------------------------------------------
// Fused pairwise attention-bias:
// bias_pre[bt,i,j,c] = p[bt,j,c] - p[bt,i,c]   (NOTE: j minus i)
// bias[bt,i,j,g] = (1/sqrt(8)) * sum_h Wbias[g,h] * prelu( sum_c bias_pre * Wemb[h,c] )
// block = 256 thr (4 waves), one block per (bt,i); wave w handles j = w,w+4,...
__global__ __launch_bounds__(256) void bias_kernel(
        const float* __restrict__ p, const float* __restrict__ Wemb,
        const float* __restrict__ prelu_a, const float* __restrict__ Wbias,
        float* __restrict__ bias) {
    int row = blockIdx.x;          // bt*19 + i
    int bt = row / V_;
    int wave = threadIdx.x >> 6;
    int lane = threadIdx.x & 63;
    __shared__ float pi[C_];
    __shared__ float pj[4][C_];
    if (threadIdx.x < C_) pi[threadIdx.x] = p[(size_t)row * C_ + threadIdx.x];
    const float a = prelu_a[0];
    const float scale = 0.35355339059327373f;   // 1/sqrt(8)
    for (int iter = 0; iter < 5; ++iter) {
        int j = wave + iter * 4;
        __syncthreads();
        if (j < V_ && lane < C_) pj[wave][lane] = p[((size_t)bt * V_ + j) * C_ + lane];
        __syncthreads();
        if (j < V_) {
            float ag[H_];
            #pragma unroll
            for (int g = 0; g < H_; ++g) ag[g] = 0.f;
            #pragma unroll
            for (int u = 0; u < 4; ++u) {
                int hh = u * 64 + lane;
                const float* wr = Wemb + (size_t)hh * C_;
                float dot = 0.f;
                #pragma unroll
                for (int c = 0; c < C_; ++c) dot += (pj[wave][c] - pi[c]) * wr[c];
                float hv = dot >= 0.f ? dot : a * dot;
                #pragma unroll
                for (int g = 0; g < H_; ++g) ag[g] += Wbias[g * HD_ + hh] * hv;
            }
            #pragma unroll
            for (int g = 0; g < H_; ++g) {
                float vv = ag[g];
                #pragma unroll
                for (int off = 32; off > 0; off >>= 1) vv += __shfl_down(vv, off, 64);
                ag[g] = vv;
            }
            if (lane == 0) {
                float* bout = bias + ((size_t)row * V_ + j) * H_;
                #pragma unroll
                for (int g = 0; g < H_; ++g) bout[g] = ag[g] * scale;
            }
        }
    }
}

// ---------------------------------------------------------------------------
// Graph attention: per (bt, h). qkv layout [rows,384]: q|k|v. scores 19x19 in LDS.
__global__ __launch_bounds__(384) void attn_graph_kernel(
        const float* __restrict__ qkv, const float* __restrict__ bias,
        float* __restrict__ out) {
    int bt = blockIdx.x;
    int h = blockIdx.y;
    __shared__ float sm[V_][V_];
    int t = threadIdx.x;
    if (t < V_ * V_) {
        int i = t / V_, j = t % V_;
        const float* q = qkv + ((size_t)(bt * V_ + i)) * 384 + h * DH_;
        const float* k = qkv + ((size_t)(bt * V_ + j)) * 384 + 128 + h * DH_;
        float s = 0.f;
        #pragma unroll
        for (int d = 0; d < DH_; ++d) s += q[d] * k[d];
        sm[i][j] = s * 0.25f + bias[((size_t)(bt * V_ + i) * V_ + j) * H_ + h];
    }
    __syncthreads();
    if (t < V_) {
        float m = -1e30f;
        for (int j = 0; j < V_; ++j) m = fmaxf(m, sm[t][j]);
        float sum = 0.f;
        for (int j = 0; j < V_; ++j) { float e = expf(sm[t][j] - m); sm[t][j] = e; sum += e; }
        float inv = 1.f / sum;
        for (int j = 0; j < V_; ++j) sm[t][j] *= inv;
    }
    __syncthreads();
    if (t < V_ * DH_) {
        int i = t / DH_, d = t % DH_;
        float o = 0.f;
        for (int j = 0; j < V_; ++j)
            o += sm[i][j] * qkv[((size_t)(bt * V_ + j)) * 384 + 256 + h * DH_ + d];
        out[((size_t)(bt * V_ + i)) * D_ + h * DH_ + d] = o;
    }
}

// Temporal attention: per (b in 304, h). scores 62x62 in LDS, no bias.
__global__ __launch_bounds__(256) void attn_temporal_kernel(
        const float* __restrict__ qkv, float* __restrict__ out) {
    int b = blockIdx.x;
    int h = blockIdx.y;
    __shared__ float sm[T_][T_];
    int tid = threadIdx.x;
    for (int idx = tid; idx < T_ * T_; idx += 256) {
        int i = idx / T_, j = idx % T_;
        const float* q = qkv + ((size_t)(b * T_ + i)) * 384 + h * DH_;
        const float* k = qkv + ((size_t)(b * T_ + j)) * 384 + 128 + h * DH_;
        float s = 0.f;
        #pragma unroll
        for (int d = 0; d < DH_; ++d) s += q[d] * k[d];
        sm[i][j] = s * 0.25f;
    }
    __syncthreads();
    for (int i = tid; i < T_; i += 256) {
        float m = -1e30f;
        for (int j = 0; j < T_; ++j) m = fmaxf(m, sm[i][j]);
        float sum = 0.f;
        for (int j = 0; j < T_; ++j) { float e = expf(sm[i][j] - m); sm[i][j] = e; sum += e; }
        float inv = 1.f / sum;
        for (int j = 0; j < T_; ++j) sm[i][j] *= inv;
    }
    __syncthreads();
    for (int idx = tid; idx < T_ * DH_; idx += 256) {
        int i = idx / DH_, d = idx % DH_;
        float o = 0.f;
        for (int j = 0; j < T_; ++j)
            o += sm[i][j] * qkv[((size_t)(b * T_ + j)) * 384 + 256 + h * DH_ + d];
        out[((size_t)(b * T_ + i)) * D_ + h * DH_ + d] = o;
    }
}

// ---------------------------------------------------------------------------
// out[row] = LN(x[row] + r[row]) * g + b   (row = 128 elems, one wave per row)
__global__ __launch_bounds__(64) void ln_add_kernel(
        const float* __restrict__ x, const float* __restrict__ r,
        const float* __restrict__ g, const float* __restrict__ b,
        float* __restrict__ out) {
    int row = blockIdx.x;
    int lane = threadIdx.x;
    const float* xr = x + (size_t)row * D_;
    const float* rr = r + (size_t)row * D_;
    float v0 = xr[lane] + rr[lane];
    float v1 = xr[lane + 64] + rr[lane + 64];
    float s = v0 + v1, sq = v0 * v0 + v1 * v1;
    #pragma unroll
    for (int off = 32; off > 0; off >>= 1) {
        s += __shfl_xor(s, off, 64);
        sq += __shfl_xor(sq, off, 64);
    }
    float mean = s * (1.f / 128.f);
    float var = sq * (1.f / 128.f) - mean * mean;
    float rstd = rsqrtf(var + 1e-5f);
    float* o = out + (size_t)row * D_;
    o[lane]      = (v0 - mean) * rstd * g[lane]      + b[lane];
    o[lane + 64] = (v1 - mean) * rstd * g[lane + 64] + b[lane + 64];
}

// y[bv,t,d] = gout[bv,t,d] + pe[t,d]
__global__ void add_pe_kernel(const float* __restrict__ gout, float* __restrict__ y) {
    int idx = blockIdx.x * 256 + threadIdx.x;
    if (idx >= ROWS * D_) return;
    int d = idx & (D_ - 1);
    int row = idx >> 7;
    int t = row % T_;
    int k2 = (d >> 1) * 2;
    float freq = expf(-(float)k2 * (9.210340371976184f / 128.f));  // ln(10000)/128
    float ang = (float)t * freq;
    float pe = (d & 1) ? cosf(ang) : sinf(ang);
    y[idx] = gout[idx] + pe;
}

__global__ void add_kernel(float* __restrict__ y, const float* __restrict__ x) {
    int idx = blockIdx.x * 256 + threadIdx.x;
    if (idx >= ROWS * D_) return;
    y[idx] += x[idx];
}

// ---------------------------------------------------------------------------
extern "C" void kernel_launch(void* const* d_in, const int* in_sizes, int n_in,
                              void* d_out, int out_size, void* d_ws, size_t ws_size,
                              hipStream_t stream) {
    const float* pose    = (const float*)d_in[0];
    const float* W_pose  = (const float*)d_in[1];
    const float* W_emb   = (const float*)d_in[2];
    const float* prelu_a = (const float*)d_in[3];
    const float* W_bias  = (const float*)d_in[4];
    const float* gWqkv   = (const float*)d_in[5];
    const float* gbqkv   = (const float*)d_in[6];
    const float* gWo     = (const float*)d_in[7];
    const float* gbo     = (const float*)d_in[8];
    const float* gln1g   = (const float*)d_in[9];
    const float* gln1b   = (const float*)d_in[10];
    const float* gW1     = (const float*)d_in[11];
    const float* gb1     = (const float*)d_in[12];
    const float* gW2     = (const float*)d_in[13];
    const float* gb2     = (const float*)d_in[14];
    const float* gln2g   = (const float*)d_in[15];
    const float* gln2b   = (const float*)d_in[16];
    const float* deW     = (const float*)d_in[17];
    const float* deb     = (const float*)d_in[18];
    const float* tWqkv   = (const float*)d_in[19];
    const float* tbqkv   = (const float*)d_in[20];
    const float* tWo     = (const float*)d_in[21];
    const float* tbo     = (const float*)d_in[22];
    const float* tln1g   = (const float*)d_in[23];
    const float* tln1b   = (const float*)d_in[24];
    const float* tW1     = (const float*)d_in[25];
    const float* tb1     = (const float*)d_in[26];
    const float* tW2     = (const float*)d_in[27];
    const float* tb2     = (const float*)d_in[28];
    const float* tln2g   = (const float*)d_in[29];
    const float* tln2b   = (const float*)d_in[30];
    const float* W_out   = (const float*)d_in[31];

    float* ws = (float*)d_ws;
    // workspace layout (floats)
    float* p    = ws;                       // 603136
    float* y    = p    + 603136;            // 2412544
    float* bias = y    + 2412544;           // 2864896
    float* qkv  = bias + 2864896;           // 7237632   (aliases: tmp, hid)
    float* tmp  = qkv;                      // 2412544
    float* hid  = qkv  + 2412544;           // 4825088
    float* attn = qkv  + 7237632;           // 2412544   (aliases: g_out)
    float* y1   = attn + 2412544;           // 2412544
    float* tmp2 = y1   + 2412544;           // 2412544
    float* outf = (float*)d_out;

    // stage 0: transpose + input embedding
    transpose_kernel<<<(B_*T_*V_*C_ + 255) / 256, 256, 0, stream>>>(pose, p);
    linear_kernel<32, 128, 0><<<ROWS, 128, 0, stream>>>(p, W_pose, nullptr, y, ROWS);

    for (int i = 0; i < 2; ++i) {
        // ---- graph encoder ----
        bias_kernel<<<BT_ * V_, 256, 0, stream>>>(
            p, W_emb + (size_t)i * HD_ * C_, prelu_a + i, W_bias + (size_t)i * H_ * HD_, bias);
        linear_kernel<128, 384, 0><<<ROWS, 384, 0, stream>>>(
            y, gWqkv + (size_t)i * 3 * D_ * D_, gbqkv + (size_t)i * 3 * D_, qkv, ROWS);
        attn_graph_kernel<<<dim3(BT_, H_), 384, 0, stream>>>(qkv, bias, attn);
        linear_kernel<128, 128, 0><<<ROWS, 128, 0, stream>>>(
            attn, gWo + (size_t)i * D_ * D_, gbo + (size_t)i * D_, tmp, ROWS);
        ln_add_kernel<<<ROWS, 64, 0, stream>>>(
            y, tmp, gln1g + (size_t)i * D_, gln1b + (size_t)i * D_, y1);
        linear_kernel<128, 256, 1><<<ROWS, 256, 0, stream>>>(
            y1, gW1 + (size_t)i * HD_ * D_, gb1 + (size_t)i * HD_, hid, ROWS);
        linear_kernel<256, 128, 0><<<ROWS, 128, 0, stream>>>(
            hid, gW2 + (size_t)i * D_ * HD_, gb2 + (size_t)i * D_, tmp, ROWS);
        ln_add_kernel<<<ROWS, 64, 0, stream>>>(
            y1, tmp, gln2g + (size_t)i * D_, gln2b + (size_t)i * D_, tmp2);
        linear_kernel<128, 128, 0><<<ROWS, 128, 0, stream>>>(
            tmp2, deW + (size_t)i * D_ * D_, deb + (size_t)i * D_, attn, ROWS);
        add_pe_kernel<<<(ROWS * D_ + 255) / 256, 256, 0, stream>>>(attn, y);   // y = mem

        // ---- temporal encoder ----
        linear_kernel<128, 384, 0><<<ROWS, 384, 0, stream>>>(
            y, tWqkv + (size_t)i * 3 * D_ * D_, tbqkv + (size_t)i * 3 * D_, qkv, ROWS);
        attn_temporal_kernel<<<dim3(BV_, H_), 256, 0, stream>>>(qkv, attn);
        linear_kernel<128, 128, 0><<<ROWS, 128, 0, stream>>>(
            attn, tWo + (size_t)i * D_ * D_, tbo + (size_t)i * D_, tmp, ROWS);
        ln_add_kernel<<<ROWS, 64, 0, stream>>>(
            y, tmp, tln1g + (size_t)i * D_, tln1b + (size_t)i * D_, y1);
        linear_kernel<128, 256, 1><<<ROWS, 256, 0, stream>>>(
            y1, tW1 + (size_t)i * HD_ * D_, tb1 + (size_t)i * HD_, hid, ROWS);
        linear_kernel<256, 128, 0><<<ROWS, 128, 0, stream>>>(
            hid, tW2 + (size_t)i * D_ * HD_, tb2 + (size_t)i * D_, tmp, ROWS);
        ln_add_kernel<<<ROWS, 64, 0, stream>>>(
            y1, tmp, tln2g + (size_t)i * D_, tln2b + (size_t)i * D_, tmp2);
        add_kernel<<<(ROWS * D_ + 255) / 256, 256, 0, stream>>>(y, tmp2);      // y += mem-resid
    }

    // final projection + LeakyReLU
    linear_kernel<128, 64, 2><<<ROWS, 64, 0, stream>>>(y, W_out, nullptr, outf, ROWS);
}

// Round 4
// 1478.755 us; speedup vs baseline: 5.2878x; 5.2878x over previous
//
#include <hip/hip_runtime.h>
#include <math.h>

// Shapes (fixed by the problem)
#define B_  16
#define C_  32
#define T_  62
#define V_  19
#define D_  128
#define HD_ 256
#define H_  8
#define DH_ 16            // D_/H_
#define ROWS 18848        // B*T*V == B*V*T  (= 8*2356)
#define BT_ 992           // B*T
#define BV_ 304           // B*V

// ---------------------------------------------------------------------------
// pose [B,C,T,V] -> p [B,T,V,C]
__global__ void transpose_kernel(const float* __restrict__ pose, float* __restrict__ p) {
    int idx = blockIdx.x * 256 + threadIdx.x;
    if (idx >= B_ * T_ * V_ * C_) return;
    int c = idx & 31;
    int rest = idx >> 5;          // b*T*V + t*V + v
    int v = rest % V_;
    int rest2 = rest / V_;
    int t = rest2 % T_;
    int b = rest2 / T_;
    p[idx] = pose[((size_t)((b * C_ + c) * T_ + t)) * V_ + v];
}

// ---------------------------------------------------------------------------
// Row-parallel linear, RP rows per block: out[r,n] = act(b[n] + sum_k in[r,k]*W[n,k])
// N threads; rows staged in LDS (broadcast reads); W read once per block (L2).
template<int K, int N, int ACT, int RP>
__global__ __launch_bounds__(N) void linear_kernel(
        const float* __restrict__ in, const float* __restrict__ W,
        const float* __restrict__ bias, float* __restrict__ out, int R) {
    __shared__ float rows[RP * K];
    int r0 = blockIdx.x * RP;
    if (r0 >= R) return;
    const float* inr = in + (size_t)r0 * K;
    for (int idx = threadIdx.x; idx < RP * K; idx += N) rows[idx] = inr[idx];
    __syncthreads();
    int n = threadIdx.x;
    float bv = bias ? bias[n] : 0.f;
    float acc[RP];
    #pragma unroll
    for (int rp = 0; rp < RP; ++rp) acc[rp] = bv;
    const float4* w4 = reinterpret_cast<const float4*>(W + (size_t)n * K);
    #pragma unroll 4
    for (int k4 = 0; k4 < K / 4; ++k4) {
        float4 w = w4[k4];
        #pragma unroll
        for (int rp = 0; rp < RP; ++rp) {
            const float4 rv = *reinterpret_cast<const float4*>(&rows[rp * K + 4 * k4]);
            acc[rp] += rv.x * w.x + rv.y * w.y + rv.z * w.z + rv.w * w.w;
        }
    }
    #pragma unroll
    for (int rp = 0; rp < RP; ++rp) {
        float v = acc[rp];
        if (ACT == 1) v = fmaxf(v, 0.f);
        if (ACT == 2) v = v >= 0.f ? v : 0.01f * v;
        out[(size_t)(r0 + rp) * N + n] = v;
    }
}

// ---------------------------------------------------------------------------
// bias2: using e = p @ Wemb^T  [BT*V, 256] (linearity of the pairwise diff):
// bias[bt,i,j,g] = scale * sum_hh Wbias[g,hh] * prelu(e[bt,j,hh] - e[bt,i,hh])
// one block per bt, one thread per (i,j) pair (361 pairs, 256 threads, 2 rounds).
// Wbias reads are block-uniform -> s_load; es padded stride 257 -> conflict-free.
__global__ __launch_bounds__(256) void bias2_kernel(
        const float* __restrict__ e, const float* __restrict__ prelu_a,
        const float* __restrict__ Wbias, float* __restrict__ bias) {
    int bt = blockIdx.x;
    __shared__ float es[V_ * 257];
    int tid = threadIdx.x;
    for (int idx = tid; idx < V_ * HD_; idx += 256) {
        int v = idx >> 8, hh = idx & 255;
        es[v * 257 + hh] = e[((size_t)(bt * V_ + v)) * HD_ + hh];
    }
    __syncthreads();
    const float a = prelu_a[0];
    const float scale = 0.35355339059327373f;   // 1/sqrt(8)
    for (int pair = tid; pair < V_ * V_; pair += 256) {
        int i = pair / V_, j = pair - i * V_;
        const float* ei = es + i * 257;
        const float* ej = es + j * 257;
        float ag[H_] = {0.f, 0.f, 0.f, 0.f, 0.f, 0.f, 0.f, 0.f};
        #pragma unroll 4
        for (int hh = 0; hh < HD_; ++hh) {
            float d = ej[hh] - ei[hh];
            float hv = d >= 0.f ? d : a * d;
            #pragma unroll
            for (int g = 0; g < H_; ++g) ag[g] += Wbias[g * HD_ + hh] * hv;
        }
        float* bout = bias + ((size_t)bt * (V_ * V_) + pair) * H_;
        #pragma unroll
        for (int g = 0; g < H_; ++g) bout[g] = ag[g] * scale;
    }
}

// ---------------------------------------------------------------------------
// Graph attention: per (bt, h). qkv layout [rows,384]: q|k|v. scores 19x19 in LDS.
__global__ __launch_bounds__(384) void attn_graph_kernel(
        const float* __restrict__ qkv, const float* __restrict__ bias,
        float* __restrict__ out) {
    int bt = blockIdx.x;
    int h = blockIdx.y;
    __shared__ float sm[V_][V_];
    int t = threadIdx.x;
    if (t < V_ * V_) {
        int i = t / V_, j = t % V_;
        const float* q = qkv + ((size_t)(bt * V_ + i)) * 384 + h * DH_;
        const float* k = qkv + ((size_t)(bt * V_ + j)) * 384 + 128 + h * DH_;
        float s = 0.f;
        #pragma unroll
        for (int d = 0; d < DH_; ++d) s += q[d] * k[d];
        sm[i][j] = s * 0.25f + bias[((size_t)(bt * V_ + i) * V_ + j) * H_ + h];
    }
    __syncthreads();
    if (t < V_) {
        float m = -1e30f;
        for (int j = 0; j < V_; ++j) m = fmaxf(m, sm[t][j]);
        float sum = 0.f;
        for (int j = 0; j < V_; ++j) { float e = expf(sm[t][j] - m); sm[t][j] = e; sum += e; }
        float inv = 1.f / sum;
        for (int j = 0; j < V_; ++j) sm[t][j] *= inv;
    }
    __syncthreads();
    if (t < V_ * DH_) {
        int i = t / DH_, d = t % DH_;
        float o = 0.f;
        for (int j = 0; j < V_; ++j)
            o += sm[i][j] * qkv[((size_t)(bt * V_ + j)) * 384 + 256 + h * DH_ + d];
        out[((size_t)(bt * V_ + i)) * D_ + h * DH_ + d] = o;
    }
}

// Temporal attention: per (b in 304, h). scores 62x62 in LDS, no bias.
__global__ __launch_bounds__(256) void attn_temporal_kernel(
        const float* __restrict__ qkv, float* __restrict__ out) {
    int b = blockIdx.x;
    int h = blockIdx.y;
    __shared__ float sm[T_][T_];
    int tid = threadIdx.x;
    for (int idx = tid; idx < T_ * T_; idx += 256) {
        int i = idx / T_, j = idx % T_;
        const float* q = qkv + ((size_t)(b * T_ + i)) * 384 + h * DH_;
        const float* k = qkv + ((size_t)(b * T_ + j)) * 384 + 128 + h * DH_;
        float s = 0.f;
        #pragma unroll
        for (int d = 0; d < DH_; ++d) s += q[d] * k[d];
        sm[i][j] = s * 0.25f;
    }
    __syncthreads();
    for (int i = tid; i < T_; i += 256) {
        float m = -1e30f;
        for (int j = 0; j < T_; ++j) m = fmaxf(m, sm[i][j]);
        float sum = 0.f;
        for (int j = 0; j < T_; ++j) { float e = expf(sm[i][j] - m); sm[i][j] = e; sum += e; }
        float inv = 1.f / sum;
        for (int j = 0; j < T_; ++j) sm[i][j] *= inv;
    }
    __syncthreads();
    for (int idx = tid; idx < T_ * DH_; idx += 256) {
        int i = idx / DH_, d = idx % DH_;
        float o = 0.f;
        for (int j = 0; j < T_; ++j)
            o += sm[i][j] * qkv[((size_t)(b * T_ + j)) * 384 + 256 + h * DH_ + d];
        out[((size_t)(b * T_ + i)) * D_ + h * DH_ + d] = o;
    }
}

// ---------------------------------------------------------------------------
// out[row] = LN(x[row] + r[row]) * g + b   (row = 128 elems, one wave per row)
__global__ __launch_bounds__(64) void ln_add_kernel(
        const float* __restrict__ x, const float* __restrict__ r,
        const float* __restrict__ g, const float* __restrict__ b,
        float* __restrict__ out) {
    int row = blockIdx.x;
    int lane = threadIdx.x;
    const float* xr = x + (size_t)row * D_;
    const float* rr = r + (size_t)row * D_;
    float v0 = xr[lane] + rr[lane];
    float v1 = xr[lane + 64] + rr[lane + 64];
    float s = v0 + v1, sq = v0 * v0 + v1 * v1;
    #pragma unroll
    for (int off = 32; off > 0; off >>= 1) {
        s += __shfl_xor(s, off, 64);
        sq += __shfl_xor(sq, off, 64);
    }
    float mean = s * (1.f / 128.f);
    float var = sq * (1.f / 128.f) - mean * mean;
    float rstd = rsqrtf(var + 1e-5f);
    float* o = out + (size_t)row * D_;
    o[lane]      = (v0 - mean) * rstd * g[lane]      + b[lane];
    o[lane + 64] = (v1 - mean) * rstd * g[lane + 64] + b[lane + 64];
}

// y[bv,t,d] = gout[bv,t,d] + pe[t,d]
__global__ void add_pe_kernel(const float* __restrict__ gout, float* __restrict__ y) {
    int idx = blockIdx.x * 256 + threadIdx.x;
    if (idx >= ROWS * D_) return;
    int d = idx & (D_ - 1);
    int row = idx >> 7;
    int t = row % T_;
    int k2 = (d >> 1) * 2;
    float freq = expf(-(float)k2 * (9.210340371976184f / 128.f));  // ln(10000)/128
    float ang = (float)t * freq;
    float pe = (d & 1) ? cosf(ang) : sinf(ang);
    y[idx] = gout[idx] + pe;
}

__global__ void add_kernel(float* __restrict__ y, const float* __restrict__ x) {
    int idx = blockIdx.x * 256 + threadIdx.x;
    if (idx >= ROWS * D_) return;
    y[idx] += x[idx];
}

// ---------------------------------------------------------------------------
extern "C" void kernel_launch(void* const* d_in, const int* in_sizes, int n_in,
                              void* d_out, int out_size, void* d_ws, size_t ws_size,
                              hipStream_t stream) {
    const float* pose    = (const float*)d_in[0];
    const float* W_pose  = (const float*)d_in[1];
    const float* W_emb   = (const float*)d_in[2];
    const float* prelu_a = (const float*)d_in[3];
    const float* W_bias  = (const float*)d_in[4];
    const float* gWqkv   = (const float*)d_in[5];
    const float* gbqkv   = (const float*)d_in[6];
    const float* gWo     = (const float*)d_in[7];
    const float* gbo     = (const float*)d_in[8];
    const float* gln1g   = (const float*)d_in[9];
    const float* gln1b   = (const float*)d_in[10];
    const float* gW1     = (const float*)d_in[11];
    const float* gb1     = (const float*)d_in[12];
    const float* gW2     = (const float*)d_in[13];
    const float* gb2     = (const float*)d_in[14];
    const float* gln2g   = (const float*)d_in[15];
    const float* gln2b   = (const float*)d_in[16];
    const float* deW     = (const float*)d_in[17];
    const float* deb     = (const float*)d_in[18];
    const float* tWqkv   = (const float*)d_in[19];
    const float* tbqkv   = (const float*)d_in[20];
    const float* tWo     = (const float*)d_in[21];
    const float* tbo     = (const float*)d_in[22];
    const float* tln1g   = (const float*)d_in[23];
    const float* tln1b   = (const float*)d_in[24];
    const float* tW1     = (const float*)d_in[25];
    const float* tb1     = (const float*)d_in[26];
    const float* tW2     = (const float*)d_in[27];
    const float* tb2     = (const float*)d_in[28];
    const float* tln2g   = (const float*)d_in[29];
    const float* tln2b   = (const float*)d_in[30];
    const float* W_out   = (const float*)d_in[31];

    float* ws = (float*)d_ws;
    // workspace layout (floats)
    float* p    = ws;                       // 603136
    float* y    = p    + 603136;            // 2412544
    float* bias = y    + 2412544;           // 2864896
    float* qkv  = bias + 2864896;           // 7237632   (aliases: tmp, hid, e)
    float* tmp  = qkv;                      // 2412544
    float* hid  = qkv  + 2412544;           // 4825088
    float* e    = qkv;                      // 4825088 (before qkv linear runs)
    float* attn = qkv  + 7237632;           // 2412544   (aliases: g_out)
    float* y1   = attn + 2412544;           // 2412544
    float* tmp2 = y1   + 2412544;           // 2412544
    float* outf = (float*)d_out;

    // stage 0: transpose + input embedding
    transpose_kernel<<<(B_*T_*V_*C_ + 255) / 256, 256, 0, stream>>>(pose, p);
    linear_kernel<32, 128, 0, 8><<<ROWS / 8, 128, 0, stream>>>(p, W_pose, nullptr, y, ROWS);

    for (int i = 0; i < 2; ++i) {
        // ---- graph encoder ----
        // e = p @ Wemb^T, then pairwise prelu-contract
        linear_kernel<32, 256, 0, 8><<<ROWS / 8, 256, 0, stream>>>(
            p, W_emb + (size_t)i * HD_ * C_, nullptr, e, ROWS);
        bias2_kernel<<<BT_, 256, 0, stream>>>(
            e, prelu_a + i, W_bias + (size_t)i * H_ * HD_, bias);
        linear_kernel<128, 384, 0, 8><<<ROWS / 8, 384, 0, stream>>>(
            y, gWqkv + (size_t)i * 3 * D_ * D_, gbqkv + (size_t)i * 3 * D_, qkv, ROWS);
        attn_graph_kernel<<<dim3(BT_, H_), 384, 0, stream>>>(qkv, bias, attn);
        linear_kernel<128, 128, 0, 8><<<ROWS / 8, 128, 0, stream>>>(
            attn, gWo + (size_t)i * D_ * D_, gbo + (size_t)i * D_, tmp, ROWS);
        ln_add_kernel<<<ROWS, 64, 0, stream>>>(
            y, tmp, gln1g + (size_t)i * D_, gln1b + (size_t)i * D_, y1);
        linear_kernel<128, 256, 1, 8><<<ROWS / 8, 256, 0, stream>>>(
            y1, gW1 + (size_t)i * HD_ * D_, gb1 + (size_t)i * HD_, hid, ROWS);
        linear_kernel<256, 128, 0, 8><<<ROWS / 8, 128, 0, stream>>>(
            hid, gW2 + (size_t)i * D_ * HD_, gb2 + (size_t)i * D_, tmp, ROWS);
        ln_add_kernel<<<ROWS, 64, 0, stream>>>(
            y1, tmp, gln2g + (size_t)i * D_, gln2b + (size_t)i * D_, tmp2);
        linear_kernel<128, 128, 0, 8><<<ROWS / 8, 128, 0, stream>>>(
            tmp2, deW + (size_t)i * D_ * D_, deb + (size_t)i * D_, attn, ROWS);
        add_pe_kernel<<<(ROWS * D_ + 255) / 256, 256, 0, stream>>>(attn, y);   // y = mem

        // ---- temporal encoder ----
        linear_kernel<128, 384, 0, 8><<<ROWS / 8, 384, 0, stream>>>(
            y, tWqkv + (size_t)i * 3 * D_ * D_, tbqkv + (size_t)i * 3 * D_, qkv, ROWS);
        attn_temporal_kernel<<<dim3(BV_, H_), 256, 0, stream>>>(qkv, attn);
        linear_kernel<128, 128, 0, 8><<<ROWS / 8, 128, 0, stream>>>(
            attn, tWo + (size_t)i * D_ * D_, tbo + (size_t)i * D_, tmp, ROWS);
        ln_add_kernel<<<ROWS, 64, 0, stream>>>(
            y, tmp, tln1g + (size_t)i * D_, tln1b + (size_t)i * D_, y1);
        linear_kernel<128, 256, 1, 8><<<ROWS / 8, 256, 0, stream>>>(
            y1, tW1 + (size_t)i * HD_ * D_, tb1 + (size_t)i * HD_, hid, ROWS);
        linear_kernel<256, 128, 0, 8><<<ROWS / 8, 128, 0, stream>>>(
            hid, tW2 + (size_t)i * D_ * HD_, tb2 + (size_t)i * D_, tmp, ROWS);
        ln_add_kernel<<<ROWS, 64, 0, stream>>>(
            y1, tmp, tln2g + (size_t)i * D_, tln2b + (size_t)i * D_, tmp2);
        add_kernel<<<(ROWS * D_ + 255) / 256, 256, 0, stream>>>(y, tmp2);      // y += mem-resid
    }

    // final projection + LeakyReLU
    linear_kernel<128, 64, 2, 8><<<ROWS / 8, 64, 0, stream>>>(y, W_out, nullptr, outf, ROWS);
}

// Round 6
// 1243.475 us; speedup vs baseline: 6.2883x; 1.1892x over previous
//
#include <hip/hip_runtime.h>
#include <math.h>

// Shapes (fixed by the problem)
#define B_  16
#define C_  32
#define T_  62
#define V_  19
#define D_  128
#define HD_ 256
#define H_  8
#define DH_ 16            // D_/H_
#define ROWS 18848        // B*T*V == B*V*T  (= 8*2356)
#define BT_ 992           // B*T
#define BV_ 304           // B*V

// ---------------------------------------------------------------------------
// pose [B,C,T,V] -> p [B,T,V,C]
__global__ void transpose_kernel(const float* __restrict__ pose, float* __restrict__ p) {
    int idx = blockIdx.x * 256 + threadIdx.x;
    if (idx >= B_ * T_ * V_ * C_) return;
    int c = idx & 31;
    int rest = idx >> 5;          // b*T*V + t*V + v
    int v = rest % V_;
    int rest2 = rest / V_;
    int t = rest2 % T_;
    int b = rest2 / T_;
    p[idx] = pose[((size_t)((b * C_ + c) * T_ + t)) * V_ + v];
}

// ---------------------------------------------------------------------------
// Row-parallel linear, RP rows per block: out[r,n] = act(b[n] + sum_k in[r,k]*W[n,k])
// N threads; rows staged in LDS (broadcast reads); W read once per block (L2).
template<int K, int N, int ACT, int RP>
__global__ __launch_bounds__(N) void linear_kernel(
        const float* __restrict__ in, const float* __restrict__ W,
        const float* __restrict__ bias, float* __restrict__ out, int R) {
    __shared__ float rows[RP * K];
    int r0 = blockIdx.x * RP;
    if (r0 >= R) return;
    const float* inr = in + (size_t)r0 * K;
    for (int idx = threadIdx.x; idx < RP * K; idx += N) rows[idx] = inr[idx];
    __syncthreads();
    int n = threadIdx.x;
    float bv = bias ? bias[n] : 0.f;
    float acc[RP];
    #pragma unroll
    for (int rp = 0; rp < RP; ++rp) acc[rp] = bv;
    const float4* w4 = reinterpret_cast<const float4*>(W + (size_t)n * K);
    #pragma unroll 4
    for (int k4 = 0; k4 < K / 4; ++k4) {
        float4 w = w4[k4];
        #pragma unroll
        for (int rp = 0; rp < RP; ++rp) {
            const float4 rv = *reinterpret_cast<const float4*>(&rows[rp * K + 4 * k4]);
            acc[rp] += rv.x * w.x + rv.y * w.y + rv.z * w.z + rv.w * w.w;
        }
    }
    #pragma unroll
    for (int rp = 0; rp < RP; ++rp) {
        float v = acc[rp];
        if (ACT == 1) v = fmaxf(v, 0.f);
        if (ACT == 2) v = v >= 0.f ? v : 0.01f * v;
        out[(size_t)(r0 + rp) * N + n] = v;
    }
}

// ---------------------------------------------------------------------------
// bias2: using e = p @ Wemb^T  [BT*V, 256] (linearity of the pairwise diff):
// bias[bt,i,j,g] = scale * sum_hh Wbias[g,hh] * prelu(e[bt,j,hh] - e[bt,i,hh])
__global__ __launch_bounds__(256) void bias2_kernel(
        const float* __restrict__ e, const float* __restrict__ prelu_a,
        const float* __restrict__ Wbias, float* __restrict__ bias) {
    int bt = blockIdx.x;
    __shared__ float es[V_ * 257];
    int tid = threadIdx.x;
    for (int idx = tid; idx < V_ * HD_; idx += 256) {
        int v = idx >> 8, hh = idx & 255;
        es[v * 257 + hh] = e[((size_t)(bt * V_ + v)) * HD_ + hh];
    }
    __syncthreads();
    const float a = prelu_a[0];
    const float scale = 0.35355339059327373f;   // 1/sqrt(8)
    for (int pair = tid; pair < V_ * V_; pair += 256) {
        int i = pair / V_, j = pair - i * V_;
        const float* ei = es + i * 257;
        const float* ej = es + j * 257;
        float ag[H_] = {0.f, 0.f, 0.f, 0.f, 0.f, 0.f, 0.f, 0.f};
        #pragma unroll 4
        for (int hh = 0; hh < HD_; ++hh) {
            float d = ej[hh] - ei[hh];
            float hv = d >= 0.f ? d : a * d;
            #pragma unroll
            for (int g = 0; g < H_; ++g) ag[g] += Wbias[g * HD_ + hh] * hv;
        }
        float* bout = bias + ((size_t)bt * (V_ * V_) + pair) * H_;
        #pragma unroll
        for (int g = 0; g < H_; ++g) bout[g] = ag[g] * scale;
    }
}

// ---------------------------------------------------------------------------
// Graph attention: per (bt, h). LDS-staged q/k/v slices, scores 19x19 in LDS.
__global__ __launch_bounds__(384) void attn_graph_kernel(
        const float* __restrict__ qkv, const float* __restrict__ bias,
        float* __restrict__ out) {
    int bt = blockIdx.x;
    int h = blockIdx.y;
    __shared__ float q_lds[V_][20];
    __shared__ float k_lds[V_][20];
    __shared__ float v_lds[V_][20];
    __shared__ float sm[V_][20];
    int tid = threadIdx.x;
    // stage: 19 rows x 4 float4 x 3 matrices = 228 vector loads
    for (int idx = tid; idx < V_ * 4 * 3; idx += 384) {
        int mat = idx / (V_ * 4);
        int rem = idx - mat * (V_ * 4);
        int row = rem >> 2, part = rem & 3;
        float4 val = *reinterpret_cast<const float4*>(
            qkv + ((size_t)(bt * V_ + row)) * 384 + mat * 128 + h * DH_ + part * 4);
        float* dst = (mat == 0 ? q_lds[row] : (mat == 1 ? k_lds[row] : v_lds[row])) + part * 4;
        *reinterpret_cast<float4*>(dst) = val;
    }
    __syncthreads();
    if (tid < V_ * V_) {
        int i = tid / V_, j = tid - i * V_;
        float acc = 0.f;
        #pragma unroll
        for (int c = 0; c < 4; ++c) {
            float4 qv = *reinterpret_cast<const float4*>(&q_lds[i][4 * c]);
            float4 kv = *reinterpret_cast<const float4*>(&k_lds[j][4 * c]);
            acc += qv.x * kv.x + qv.y * kv.y + qv.z * kv.z + qv.w * kv.w;
        }
        sm[i][j] = acc * 0.25f + bias[((size_t)(bt * V_ + i) * V_ + j) * H_ + h];
    }
    __syncthreads();
    if (tid < V_) {
        float m = -1e30f;
        for (int j = 0; j < V_; ++j) m = fmaxf(m, sm[tid][j]);
        float sum = 0.f;
        for (int j = 0; j < V_; ++j) { float e = __expf(sm[tid][j] - m); sm[tid][j] = e; sum += e; }
        float inv = 1.f / sum;
        for (int j = 0; j < V_; ++j) sm[tid][j] *= inv;
    }
    __syncthreads();
    if (tid < V_ * DH_) {
        int i = tid / DH_, d = tid - i * DH_;
        float o = 0.f;
        #pragma unroll 4
        for (int j = 0; j < V_; ++j) o += sm[i][j] * v_lds[j][d];
        out[((size_t)(bt * V_ + i)) * D_ + h * DH_ + d] = o;
    }
}

// ---------------------------------------------------------------------------
// Temporal attention: per (b, h). LDS-staged q/k/v; softmax in registers.
// Score/softmax phase: thread (i, jt) = (tid>>2, tid&3), jt owns j in [16*jt, ...).
// PV phase: thread (i, dg), output float4.
__global__ __launch_bounds__(256) void attn_temporal_kernel(
        const float* __restrict__ qkv, float* __restrict__ out) {
    int b = blockIdx.x;
    int h = blockIdx.y;
    __shared__ float q_lds[T_][20];
    __shared__ float k_lds[T_][20];
    __shared__ float v_lds[T_][20];
    __shared__ float sm[T_][68];
    int tid = threadIdx.x;
    // stage: 62 rows x 4 float4 x 3 matrices = 744 vector loads
    for (int idx = tid; idx < T_ * 4 * 3; idx += 256) {
        int mat = idx / (T_ * 4);
        int rem = idx - mat * (T_ * 4);
        int row = rem >> 2, part = rem & 3;
        float4 val = *reinterpret_cast<const float4*>(
            qkv + ((size_t)(b * T_ + row)) * 384 + mat * 128 + h * DH_ + part * 4);
        float* dst = (mat == 0 ? q_lds[row] : (mat == 1 ? k_lds[row] : v_lds[row])) + part * 4;
        *reinterpret_cast<float4*>(dst) = val;
    }
    __syncthreads();
    if (tid < T_ * 4) {
        int i = tid >> 2, jt = tid & 3;
        int j0 = jt * 16;
        int jn = (j0 + 16 <= T_) ? 16 : (T_ - j0);   // 16,16,16,14
        // q row scaled by 1/sqrt(d) once
        float qreg[16];
        #pragma unroll
        for (int c = 0; c < 4; ++c) {
            float4 qv = *reinterpret_cast<const float4*>(&q_lds[i][4 * c]);
            qreg[4 * c + 0] = qv.x * 0.25f;
            qreg[4 * c + 1] = qv.y * 0.25f;
            qreg[4 * c + 2] = qv.z * 0.25f;
            qreg[4 * c + 3] = qv.w * 0.25f;
        }
        float s[16];
        #pragma unroll
        for (int jj = 0; jj < 16; ++jj) {
            float acc = -1e30f;
            if (jj < jn) {
                acc = 0.f;
                const float* kr = k_lds[j0 + jj];
                #pragma unroll
                for (int c = 0; c < 4; ++c) {
                    float4 kv = *reinterpret_cast<const float4*>(&kr[4 * c]);
                    acc += qreg[4*c+0] * kv.x + qreg[4*c+1] * kv.y
                         + qreg[4*c+2] * kv.z + qreg[4*c+3] * kv.w;
                }
            }
            s[jj] = acc;
        }
        // softmax in registers: reduce over 16 regs + 4 lanes of this row
        float m = -1e30f;
        #pragma unroll
        for (int jj = 0; jj < 16; ++jj) m = fmaxf(m, s[jj]);
        m = fmaxf(m, __shfl_xor(m, 1, 64));
        m = fmaxf(m, __shfl_xor(m, 2, 64));
        float sum = 0.f;
        #pragma unroll
        for (int jj = 0; jj < 16; ++jj) {
            float e = (jj < jn) ? __expf(s[jj] - m) : 0.f;
            s[jj] = e;
            sum += e;
        }
        sum += __shfl_xor(sum, 1, 64);
        sum += __shfl_xor(sum, 2, 64);
        float inv = 1.f / sum;
        #pragma unroll
        for (int jj = 0; jj < 16; ++jj) s[jj] *= inv;
        #pragma unroll
        for (int c = 0; c < 4; ++c)
            *reinterpret_cast<float4*>(&sm[i][j0 + 4 * c]) =
                *reinterpret_cast<const float4*>(&s[4 * c]);
    }
    __syncthreads();
    if (tid < T_ * 4) {
        int i = tid >> 2, dg = tid & 3;
        float4 o = {0.f, 0.f, 0.f, 0.f};
        for (int j = 0; j < T_; ++j) {
            float pp = sm[i][j];
            const float4 vv = *reinterpret_cast<const float4*>(&v_lds[j][4 * dg]);
            o.x += pp * vv.x; o.y += pp * vv.y; o.z += pp * vv.z; o.w += pp * vv.w;
        }
        *reinterpret_cast<float4*>(out + ((size_t)(b * T_ + i)) * D_ + h * DH_ + 4 * dg) = o;
    }
}

// ---------------------------------------------------------------------------
// out[row] = LN(x[row] + r[row]) * g + b   (row = 128 elems, one wave per row)
__global__ __launch_bounds__(64) void ln_add_kernel(
        const float* __restrict__ x, const float* __restrict__ r,
        const float* __restrict__ g, const float* __restrict__ b,
        float* __restrict__ out) {
    int row = blockIdx.x;
    int lane = threadIdx.x;
    const float* xr = x + (size_t)row * D_;
    const float* rr = r + (size_t)row * D_;
    float v0 = xr[lane] + rr[lane];
    float v1 = xr[lane + 64] + rr[lane + 64];
    float s = v0 + v1, sq = v0 * v0 + v1 * v1;
    #pragma unroll
    for (int off = 32; off > 0; off >>= 1) {
        s += __shfl_xor(s, off, 64);
        sq += __shfl_xor(sq, off, 64);
    }
    float mean = s * (1.f / 128.f);
    float var = sq * (1.f / 128.f) - mean * mean;
    float rstd = rsqrtf(var + 1e-5f);
    float* o = out + (size_t)row * D_;
    o[lane]      = (v0 - mean) * rstd * g[lane]      + b[lane];
    o[lane + 64] = (v1 - mean) * rstd * g[lane + 64] + b[lane + 64];
}

// y[bv,t,d] = gout[bv,t,d] + pe[t,d]
__global__ void add_pe_kernel(const float* __restrict__ gout, float* __restrict__ y) {
    int idx = blockIdx.x * 256 + threadIdx.x;
    if (idx >= ROWS * D_) return;
    int d = idx & (D_ - 1);
    int row = idx >> 7;
    int t = row % T_;
    int k2 = (d >> 1) * 2;
    float freq = expf(-(float)k2 * (9.210340371976184f / 128.f));  // ln(10000)/128
    float ang = (float)t * freq;
    float pe = (d & 1) ? cosf(ang) : sinf(ang);
    y[idx] = gout[idx] + pe;
}

__global__ void add_kernel(float* __restrict__ y, const float* __restrict__ x) {
    int idx = blockIdx.x * 256 + threadIdx.x;
    if (idx >= ROWS * D_) return;
    y[idx] += x[idx];
}

// ---------------------------------------------------------------------------
extern "C" void kernel_launch(void* const* d_in, const int* in_sizes, int n_in,
                              void* d_out, int out_size, void* d_ws, size_t ws_size,
                              hipStream_t stream) {
    const float* pose    = (const float*)d_in[0];
    const float* W_pose  = (const float*)d_in[1];
    const float* W_emb   = (const float*)d_in[2];
    const float* prelu_a = (const float*)d_in[3];
    const float* W_bias  = (const float*)d_in[4];
    const float* gWqkv   = (const float*)d_in[5];
    const float* gbqkv   = (const float*)d_in[6];
    const float* gWo     = (const float*)d_in[7];
    const float* gbo     = (const float*)d_in[8];
    const float* gln1g   = (const float*)d_in[9];
    const float* gln1b   = (const float*)d_in[10];
    const float* gW1     = (const float*)d_in[11];
    const float* gb1     = (const float*)d_in[12];
    const float* gW2     = (const float*)d_in[13];
    const float* gb2     = (const float*)d_in[14];
    const float* gln2g   = (const float*)d_in[15];
    const float* gln2b   = (const float*)d_in[16];
    const float* deW     = (const float*)d_in[17];
    const float* deb     = (const float*)d_in[18];
    const float* tWqkv   = (const float*)d_in[19];
    const float* tbqkv   = (const float*)d_in[20];
    const float* tWo     = (const float*)d_in[21];
    const float* tbo     = (const float*)d_in[22];
    const float* tln1g   = (const float*)d_in[23];
    const float* tln1b   = (const float*)d_in[24];
    const float* tW1     = (const float*)d_in[25];
    const float* tb1     = (const float*)d_in[26];
    const float* tW2     = (const float*)d_in[27];
    const float* tb2     = (const float*)d_in[28];
    const float* tln2g   = (const float*)d_in[29];
    const float* tln2b   = (const float*)d_in[30];
    const float* W_out   = (const float*)d_in[31];

    float* ws = (float*)d_ws;
    // workspace layout (floats)
    float* p    = ws;                       // 603136
    float* y    = p    + 603136;            // 2412544
    float* bias = y    + 2412544;           // 2864896
    float* qkv  = bias + 2864896;           // 7237632   (aliases: tmp, hid, e)
    float* tmp  = qkv;                      // 2412544
    float* hid  = qkv  + 2412544;           // 4825088
    float* e    = qkv;                      // 4825088 (before qkv linear runs)
    float* attn = qkv  + 7237632;           // 2412544   (aliases: g_out)
    float* y1   = attn + 2412544;           // 2412544
    float* tmp2 = y1   + 2412544;           // 2412544
    float* outf = (float*)d_out;

    // stage 0: transpose + input embedding
    transpose_kernel<<<(B_*T_*V_*C_ + 255) / 256, 256, 0, stream>>>(pose, p);
    linear_kernel<32, 128, 0, 8><<<ROWS / 8, 128, 0, stream>>>(p, W_pose, nullptr, y, ROWS);

    for (int i = 0; i < 2; ++i) {
        // ---- graph encoder ----
        // e = p @ Wemb^T, then pairwise prelu-contract
        linear_kernel<32, 256, 0, 8><<<ROWS / 8, 256, 0, stream>>>(
            p, W_emb + (size_t)i * HD_ * C_, nullptr, e, ROWS);
        bias2_kernel<<<BT_, 256, 0, stream>>>(
            e, prelu_a + i, W_bias + (size_t)i * H_ * HD_, bias);
        linear_kernel<128, 384, 0, 8><<<ROWS / 8, 384, 0, stream>>>(
            y, gWqkv + (size_t)i * 3 * D_ * D_, gbqkv + (size_t)i * 3 * D_, qkv, ROWS);
        attn_graph_kernel<<<dim3(BT_, H_), 384, 0, stream>>>(qkv, bias, attn);
        linear_kernel<128, 128, 0, 8><<<ROWS / 8, 128, 0, stream>>>(
            attn, gWo + (size_t)i * D_ * D_, gbo + (size_t)i * D_, tmp, ROWS);
        ln_add_kernel<<<ROWS, 64, 0, stream>>>(
            y, tmp, gln1g + (size_t)i * D_, gln1b + (size_t)i * D_, y1);
        linear_kernel<128, 256, 1, 8><<<ROWS / 8, 256, 0, stream>>>(
            y1, gW1 + (size_t)i * HD_ * D_, gb1 + (size_t)i * HD_, hid, ROWS);
        linear_kernel<256, 128, 0, 8><<<ROWS / 8, 128, 0, stream>>>(
            hid, gW2 + (size_t)i * D_ * HD_, gb2 + (size_t)i * D_, tmp, ROWS);
        ln_add_kernel<<<ROWS, 64, 0, stream>>>(
            y1, tmp, gln2g + (size_t)i * D_, gln2b + (size_t)i * D_, tmp2);
        linear_kernel<128, 128, 0, 8><<<ROWS / 8, 128, 0, stream>>>(
            tmp2, deW + (size_t)i * D_ * D_, deb + (size_t)i * D_, attn, ROWS);
        add_pe_kernel<<<(ROWS * D_ + 255) / 256, 256, 0, stream>>>(attn, y);   // y = mem

        // ---- temporal encoder ----
        linear_kernel<128, 384, 0, 8><<<ROWS / 8, 384, 0, stream>>>(
            y, tWqkv + (size_t)i * 3 * D_ * D_, tbqkv + (size_t)i * 3 * D_, qkv, ROWS);
        attn_temporal_kernel<<<dim3(BV_, H_), 256, 0, stream>>>(qkv, attn);
        linear_kernel<128, 128, 0, 8><<<ROWS / 8, 128, 0, stream>>>(
            attn, tWo + (size_t)i * D_ * D_, tbo + (size_t)i * D_, tmp, ROWS);
        ln_add_kernel<<<ROWS, 64, 0, stream>>>(
            y, tmp, tln1g + (size_t)i * D_, tln1b + (size_t)i * D_, y1);
        linear_kernel<128, 256, 1, 8><<<ROWS / 8, 256, 0, stream>>>(
            y1, tW1 + (size_t)i * HD_ * D_, tb1 + (size_t)i * HD_, hid, ROWS);
        linear_kernel<256, 128, 0, 8><<<ROWS / 8, 128, 0, stream>>>(
            hid, tW2 + (size_t)i * D_ * HD_, tb2 + (size_t)i * D_, tmp, ROWS);
        ln_add_kernel<<<ROWS, 64, 0, stream>>>(
            y1, tmp, tln2g + (size_t)i * D_, tln2b + (size_t)i * D_, tmp2);
        add_kernel<<<(ROWS * D_ + 255) / 256, 256, 0, stream>>>(y, tmp2);      // y += mem-resid
    }

    // final projection + LeakyReLU
    linear_kernel<128, 64, 2, 8><<<ROWS / 8, 64, 0, stream>>>(y, W_out, nullptr, outf, ROWS);
}

// Round 7
// 812.751 us; speedup vs baseline: 9.6209x; 1.5300x over previous
//
#include <hip/hip_runtime.h>
#include <hip/hip_bf16.h>
#include <math.h>

// Shapes (fixed by the problem)
#define B_  16
#define C_  32
#define T_  62
#define V_  19
#define D_  128
#define HD_ 256
#define H_  8
#define DH_ 16            // D_/H_
#define ROWS 18848        // B*T*V == B*V*T  (= 16*1178)
#define RT_  1178         // ROWS/16 row-tiles
#define BT_ 992           // B*T
#define BV_ 304           // B*V

typedef __attribute__((ext_vector_type(8))) short short8v;   // 8 bf16 (4 VGPRs)
typedef __attribute__((ext_vector_type(4))) float f32x4;

struct alignas(8) bf4 { __hip_bfloat16 x, y, z, w; };

// ---------------------------------------------------------------------------
// pose [B,C,T,V] -> p_bf [B,T,V,C] (bf16; only consumed by bf16 GEMMs)
__global__ void transpose_kernel(const float* __restrict__ pose, __hip_bfloat16* __restrict__ p_bf) {
    int idx = blockIdx.x * 256 + threadIdx.x;
    if (idx >= B_ * T_ * V_ * C_) return;
    int c = idx & 31;
    int rest = idx >> 5;          // b*T*V + t*V + v
    int v = rest % V_;
    int rest2 = rest / V_;
    int t = rest2 % T_;
    int b = rest2 / T_;
    p_bf[idx] = __float2bfloat16(pose[((size_t)((b * C_ + c) * T_ + t)) * V_ + v]);
}

// ---------------------------------------------------------------------------
// Convert all weight matrices to bf16 into one contiguous buffer (one launch).
// Segment offsets (elems): see host side.
__global__ void wconv_kernel(
        const float* s0, const float* s1, const float* s2, const float* s3,
        const float* s4, const float* s5, const float* s6, const float* s7,
        const float* s8, const float* s9, const float* s10, const float* s11,
        __hip_bfloat16* __restrict__ dst) {
    int idx = blockIdx.x * 256 + threadIdx.x;
    if (idx >= 585728) return;
    const float* s; int base;
    if      (idx <   4096) { s = s0;  base = 0;      }
    else if (idx <  20480) { s = s1;  base = 4096;   }
    else if (idx < 118784) { s = s2;  base = 20480;  }
    else if (idx < 151552) { s = s3;  base = 118784; }
    else if (idx < 217088) { s = s4;  base = 151552; }
    else if (idx < 282624) { s = s5;  base = 217088; }
    else if (idx < 315392) { s = s6;  base = 282624; }
    else if (idx < 413696) { s = s7;  base = 315392; }
    else if (idx < 446464) { s = s8;  base = 413696; }
    else if (idx < 512000) { s = s9;  base = 446464; }
    else if (idx < 577536) { s = s10; base = 512000; }
    else                   { s = s11; base = 577536; }
    dst[idx] = __float2bfloat16(s[idx - base]);
}

// ---------------------------------------------------------------------------
// MFMA linear: out[r,n] = act(bias[n] + sum_k A[r,k]*W[n,k]), A/W bf16, acc fp32.
// One wave per 16x16 tile; grid = (RT_, N/64); wave w -> n-tile blockIdx.y*4+w.
// mfma_f32_16x16x32_bf16 layout: A lane->(row=l&15, k=(l>>4)*8+0..7);
// B from row-major W[n,k] identically; C/D: col=l&15, row=(l>>4)*4+reg.
template<int N, int K, int ACT, bool HASBIAS, bool O32, bool O16>
__global__ __launch_bounds__(256) void mfma_linear(
        const __hip_bfloat16* __restrict__ A, const __hip_bfloat16* __restrict__ W,
        const float* __restrict__ bias, float* __restrict__ out32,
        __hip_bfloat16* __restrict__ out16) {
    int wave = threadIdx.x >> 6;
    int lane = threadIdx.x & 63;
    int rt = blockIdx.x;
    int nt = blockIdx.y * 4 + wave;
    int r0 = rt * 16, n0 = nt * 16;
    int rl = lane & 15;
    int kk = (lane >> 4) * 8;
    const short* Ab = (const short*)A + (size_t)(r0 + rl) * K + kk;
    const short* Wb = (const short*)W + (size_t)(n0 + rl) * K + kk;
    f32x4 acc = {0.f, 0.f, 0.f, 0.f};
    #pragma unroll
    for (int kb = 0; kb < K / 32; ++kb) {
        short8v a = *reinterpret_cast<const short8v*>(Ab + kb * 32);
        short8v b = *reinterpret_cast<const short8v*>(Wb + kb * 32);
        acc = __builtin_amdgcn_mfma_f32_16x16x32_bf16(a, b, acc, 0, 0, 0);
    }
    int oc = n0 + rl;
    int or0 = r0 + (lane >> 4) * 4;
    float bv = HASBIAS ? bias[oc] : 0.f;
    #pragma unroll
    for (int j = 0; j < 4; ++j) {
        float v = acc[j] + bv;
        if (ACT == 1) v = fmaxf(v, 0.f);
        if (ACT == 2) v = v >= 0.f ? v : 0.01f * v;
        if (O32) out32[(size_t)(or0 + j) * N + oc] = v;
        if (O16) out16[(size_t)(or0 + j) * N + oc] = __float2bfloat16(v);
    }
}

// ---------------------------------------------------------------------------
// bias2: using e = p @ Wemb^T  [BT*V, 256] (linearity of the pairwise diff):
// bias[bt,i,j,g] = scale * sum_hh Wbias[g,hh] * prelu(e[bt,j,hh] - e[bt,i,hh])
__global__ __launch_bounds__(256) void bias2_kernel(
        const float* __restrict__ e, const float* __restrict__ prelu_a,
        const float* __restrict__ Wbias, float* __restrict__ bias) {
    int bt = blockIdx.x;
    __shared__ float es[V_ * 257];
    int tid = threadIdx.x;
    for (int idx = tid; idx < V_ * HD_; idx += 256) {
        int v = idx >> 8, hh = idx & 255;
        es[v * 257 + hh] = e[((size_t)(bt * V_ + v)) * HD_ + hh];
    }
    __syncthreads();
    const float a = prelu_a[0];
    const float scale = 0.35355339059327373f;   // 1/sqrt(8)
    for (int pair = tid; pair < V_ * V_; pair += 256) {
        int i = pair / V_, j = pair - i * V_;
        const float* ei = es + i * 257;
        const float* ej = es + j * 257;
        float ag[H_] = {0.f, 0.f, 0.f, 0.f, 0.f, 0.f, 0.f, 0.f};
        #pragma unroll 4
        for (int hh = 0; hh < HD_; ++hh) {
            float d = ej[hh] - ei[hh];
            float hv = d >= 0.f ? d : a * d;
            #pragma unroll
            for (int g = 0; g < H_; ++g) ag[g] += Wbias[g * HD_ + hh] * hv;
        }
        float* bout = bias + ((size_t)bt * (V_ * V_) + pair) * H_;
        #pragma unroll
        for (int g = 0; g < H_; ++g) bout[g] = ag[g] * scale;
    }
}

// ---------------------------------------------------------------------------
// Graph attention: per (bt, h). LDS-staged q/k/v, scores 19x19 in LDS. bf16 out.
__global__ __launch_bounds__(384) void attn_graph_kernel(
        const float* __restrict__ qkv, const float* __restrict__ bias,
        __hip_bfloat16* __restrict__ out) {
    int bt = blockIdx.x;
    int h = blockIdx.y;
    __shared__ float q_lds[V_][20];
    __shared__ float k_lds[V_][20];
    __shared__ float v_lds[V_][20];
    __shared__ float sm[V_][20];
    int tid = threadIdx.x;
    for (int idx = tid; idx < V_ * 4 * 3; idx += 384) {
        int mat = idx / (V_ * 4);
        int rem = idx - mat * (V_ * 4);
        int row = rem >> 2, part = rem & 3;
        float4 val = *reinterpret_cast<const float4*>(
            qkv + ((size_t)(bt * V_ + row)) * 384 + mat * 128 + h * DH_ + part * 4);
        float* dst = (mat == 0 ? q_lds[row] : (mat == 1 ? k_lds[row] : v_lds[row])) + part * 4;
        *reinterpret_cast<float4*>(dst) = val;
    }
    __syncthreads();
    if (tid < V_ * V_) {
        int i = tid / V_, j = tid - i * V_;
        float acc = 0.f;
        #pragma unroll
        for (int c = 0; c < 4; ++c) {
            float4 qv = *reinterpret_cast<const float4*>(&q_lds[i][4 * c]);
            float4 kv = *reinterpret_cast<const float4*>(&k_lds[j][4 * c]);
            acc += qv.x * kv.x + qv.y * kv.y + qv.z * kv.z + qv.w * kv.w;
        }
        sm[i][j] = acc * 0.25f + bias[((size_t)(bt * V_ + i) * V_ + j) * H_ + h];
    }
    __syncthreads();
    if (tid < V_) {
        float m = -1e30f;
        for (int j = 0; j < V_; ++j) m = fmaxf(m, sm[tid][j]);
        float sum = 0.f;
        for (int j = 0; j < V_; ++j) { float e = __expf(sm[tid][j] - m); sm[tid][j] = e; sum += e; }
        float inv = 1.f / sum;
        for (int j = 0; j < V_; ++j) sm[tid][j] *= inv;
    }
    __syncthreads();
    if (tid < V_ * DH_) {
        int i = tid / DH_, d = tid - i * DH_;
        float o = 0.f;
        #pragma unroll 4
        for (int j = 0; j < V_; ++j) o += sm[i][j] * v_lds[j][d];
        out[((size_t)(bt * V_ + i)) * D_ + h * DH_ + d] = __float2bfloat16(o);
    }
}

// ---------------------------------------------------------------------------
// Temporal attention: per (b, h). LDS-staged q/k/v; softmax in registers. bf16 out.
__global__ __launch_bounds__(256) void attn_temporal_kernel(
        const float* __restrict__ qkv, __hip_bfloat16* __restrict__ out) {
    int b = blockIdx.x;
    int h = blockIdx.y;
    __shared__ float q_lds[T_][20];
    __shared__ float k_lds[T_][20];
    __shared__ float v_lds[T_][20];
    __shared__ float sm[T_][68];
    int tid = threadIdx.x;
    for (int idx = tid; idx < T_ * 4 * 3; idx += 256) {
        int mat = idx / (T_ * 4);
        int rem = idx - mat * (T_ * 4);
        int row = rem >> 2, part = rem & 3;
        float4 val = *reinterpret_cast<const float4*>(
            qkv + ((size_t)(b * T_ + row)) * 384 + mat * 128 + h * DH_ + part * 4);
        float* dst = (mat == 0 ? q_lds[row] : (mat == 1 ? k_lds[row] : v_lds[row])) + part * 4;
        *reinterpret_cast<float4*>(dst) = val;
    }
    __syncthreads();
    if (tid < T_ * 4) {
        int i = tid >> 2, jt = tid & 3;
        int j0 = jt * 16;
        int jn = (j0 + 16 <= T_) ? 16 : (T_ - j0);   // 16,16,16,14
        float qreg[16];
        #pragma unroll
        for (int c = 0; c < 4; ++c) {
            float4 qv = *reinterpret_cast<const float4*>(&q_lds[i][4 * c]);
            qreg[4 * c + 0] = qv.x * 0.25f;
            qreg[4 * c + 1] = qv.y * 0.25f;
            qreg[4 * c + 2] = qv.z * 0.25f;
            qreg[4 * c + 3] = qv.w * 0.25f;
        }
        float s[16];
        #pragma unroll
        for (int jj = 0; jj < 16; ++jj) {
            float acc = -1e30f;
            if (jj < jn) {
                acc = 0.f;
                const float* kr = k_lds[j0 + jj];
                #pragma unroll
                for (int c = 0; c < 4; ++c) {
                    float4 kv = *reinterpret_cast<const float4*>(&kr[4 * c]);
                    acc += qreg[4*c+0] * kv.x + qreg[4*c+1] * kv.y
                         + qreg[4*c+2] * kv.z + qreg[4*c+3] * kv.w;
                }
            }
            s[jj] = acc;
        }
        float m = -1e30f;
        #pragma unroll
        for (int jj = 0; jj < 16; ++jj) m = fmaxf(m, s[jj]);
        m = fmaxf(m, __shfl_xor(m, 1, 64));
        m = fmaxf(m, __shfl_xor(m, 2, 64));
        float sum = 0.f;
        #pragma unroll
        for (int jj = 0; jj < 16; ++jj) {
            float e = (jj < jn) ? __expf(s[jj] - m) : 0.f;
            s[jj] = e;
            sum += e;
        }
        sum += __shfl_xor(sum, 1, 64);
        sum += __shfl_xor(sum, 2, 64);
        float inv = 1.f / sum;
        #pragma unroll
        for (int jj = 0; jj < 16; ++jj) s[jj] *= inv;
        #pragma unroll
        for (int c = 0; c < 4; ++c)
            *reinterpret_cast<float4*>(&sm[i][j0 + 4 * c]) =
                *reinterpret_cast<const float4*>(&s[4 * c]);
    }
    __syncthreads();
    if (tid < T_ * 4) {
        int i = tid >> 2, dg = tid & 3;
        float4 o = {0.f, 0.f, 0.f, 0.f};
        for (int j = 0; j < T_; ++j) {
            float pp = sm[i][j];
            const float4 vv = *reinterpret_cast<const float4*>(&v_lds[j][4 * dg]);
            o.x += pp * vv.x; o.y += pp * vv.y; o.z += pp * vv.z; o.w += pp * vv.w;
        }
        bf4 ov = { __float2bfloat16(o.x), __float2bfloat16(o.y),
                   __float2bfloat16(o.z), __float2bfloat16(o.w) };
        *reinterpret_cast<bf4*>(out + ((size_t)(b * T_ + i)) * D_ + h * DH_ + 4 * dg) = ov;
    }
}

// ---------------------------------------------------------------------------
// out = LN(x + r) * g + b; optionally fp32 and/or bf16 outputs.
template<bool O32, bool O16>
__global__ __launch_bounds__(64) void ln_add_kernel(
        const float* __restrict__ x, const float* __restrict__ r,
        const float* __restrict__ g, const float* __restrict__ b,
        float* __restrict__ o32, __hip_bfloat16* __restrict__ o16) {
    int row = blockIdx.x;
    int lane = threadIdx.x;
    const float* xr = x + (size_t)row * D_;
    const float* rr = r + (size_t)row * D_;
    float v0 = xr[lane] + rr[lane];
    float v1 = xr[lane + 64] + rr[lane + 64];
    float s = v0 + v1, sq = v0 * v0 + v1 * v1;
    #pragma unroll
    for (int off = 32; off > 0; off >>= 1) {
        s += __shfl_xor(s, off, 64);
        sq += __shfl_xor(sq, off, 64);
    }
    float mean = s * (1.f / 128.f);
    float var = sq * (1.f / 128.f) - mean * mean;
    float rstd = rsqrtf(var + 1e-5f);
    float a0 = (v0 - mean) * rstd * g[lane]      + b[lane];
    float a1 = (v1 - mean) * rstd * g[lane + 64] + b[lane + 64];
    if (O32) {
        float* o = o32 + (size_t)row * D_;
        o[lane] = a0; o[lane + 64] = a1;
    }
    if (O16) {
        __hip_bfloat16* o = o16 + (size_t)row * D_;
        o[lane] = __float2bfloat16(a0); o[lane + 64] = __float2bfloat16(a1);
    }
}

// y = gout + pe  (fp32 + bf16 copies)
__global__ void add_pe_kernel(const float* __restrict__ gout,
                              float* __restrict__ y, __hip_bfloat16* __restrict__ y_bf) {
    int idx = blockIdx.x * 256 + threadIdx.x;
    if (idx >= ROWS * D_) return;
    int d = idx & (D_ - 1);
    int row = idx >> 7;
    int t = row % T_;
    int k2 = (d >> 1) * 2;
    float freq = expf(-(float)k2 * (9.210340371976184f / 128.f));  // ln(10000)/128
    float ang = (float)t * freq;
    float pe = (d & 1) ? cosf(ang) : sinf(ang);
    float v = gout[idx] + pe;
    y[idx] = v;
    y_bf[idx] = __float2bfloat16(v);
}

// y += x  (fp32 + bf16 copies)
__global__ void add_kernel(float* __restrict__ y, __hip_bfloat16* __restrict__ y_bf,
                           const float* __restrict__ x) {
    int idx = blockIdx.x * 256 + threadIdx.x;
    if (idx >= ROWS * D_) return;
    float v = y[idx] + x[idx];
    y[idx] = v;
    y_bf[idx] = __float2bfloat16(v);
}

// ---------------------------------------------------------------------------
extern "C" void kernel_launch(void* const* d_in, const int* in_sizes, int n_in,
                              void* d_out, int out_size, void* d_ws, size_t ws_size,
                              hipStream_t stream) {
    const float* pose    = (const float*)d_in[0];
    const float* W_pose  = (const float*)d_in[1];
    const float* W_emb   = (const float*)d_in[2];
    const float* prelu_a = (const float*)d_in[3];
    const float* W_bias  = (const float*)d_in[4];
    const float* gWqkv   = (const float*)d_in[5];
    const float* gbqkv   = (const float*)d_in[6];
    const float* gWo     = (const float*)d_in[7];
    const float* gbo     = (const float*)d_in[8];
    const float* gln1g   = (const float*)d_in[9];
    const float* gln1b   = (const float*)d_in[10];
    const float* gW1     = (const float*)d_in[11];
    const float* gb1     = (const float*)d_in[12];
    const float* gW2     = (const float*)d_in[13];
    const float* gb2     = (const float*)d_in[14];
    const float* gln2g   = (const float*)d_in[15];
    const float* gln2b   = (const float*)d_in[16];
    const float* deW     = (const float*)d_in[17];
    const float* deb     = (const float*)d_in[18];
    const float* tWqkv   = (const float*)d_in[19];
    const float* tbqkv   = (const float*)d_in[20];
    const float* tWo     = (const float*)d_in[21];
    const float* tbo     = (const float*)d_in[22];
    const float* tln1g   = (const float*)d_in[23];
    const float* tln1b   = (const float*)d_in[24];
    const float* tW1     = (const float*)d_in[25];
    const float* tb1     = (const float*)d_in[26];
    const float* tW2     = (const float*)d_in[27];
    const float* tb2     = (const float*)d_in[28];
    const float* tln2g   = (const float*)d_in[29];
    const float* tln2b   = (const float*)d_in[30];
    const float* W_out   = (const float*)d_in[31];

    float* ws = (float*)d_ws;
    // workspace layout (float-slot offsets); total 17,934,592 floats = 71.7 MB
    __hip_bfloat16* p_bf   = (__hip_bfloat16*)(ws + 0);          // ROWS*32 bf16
    float*          y      = ws + 301568;                        // ROWS*128 f32
    __hip_bfloat16* y_bf   = (__hip_bfloat16*)(ws + 2714112);    // ROWS*128 bf16
    float*          biasbuf= ws + 3920384;                       // BT*361*8 f32
    float*          big    = ws + 6785280;                       // 7,237,632 f32
    float*          e      = big;                                // ROWS*256 f32 (pre-qkv)
    float*          qkvf   = big;                                // ROWS*384 f32
    float*          tmp    = big;                                // ROWS*128 f32 (post-attn)
    __hip_bfloat16* hid_bf = (__hip_bfloat16*)(big + 2412544);   // ROWS*256 bf16
    float*          y1     = big + 4825088;                      // ROWS*128 f32
    __hip_bfloat16* attn_bf= (__hip_bfloat16*)(ws + 14022912);   // ROWS*128 bf16
    float*          t2     = ws + 15229184;                      // ROWS*128 f32 region
    __hip_bfloat16* y1_bf  = (__hip_bfloat16*)t2;                // (phase-disjoint with t2)
    __hip_bfloat16* t2_bf  = (__hip_bfloat16*)t2;
    __hip_bfloat16* w_bf   = (__hip_bfloat16*)(ws + 17641728);   // 585,728 bf16 weights
    float*          outf   = (float*)d_out;

    // bf16 weight offsets (elems)
    const int oWpose = 0, oWemb = 4096, oGqkv = 20480, oGwo = 118784, oGw1 = 151552,
              oGw2 = 217088, oDe = 282624, oTqkv = 315392, oTwo = 413696,
              oTw1 = 446464, oTw2 = 512000, oWout = 577536;

    wconv_kernel<<<(585728 + 255) / 256, 256, 0, stream>>>(
        W_pose, W_emb, gWqkv, gWo, gW1, gW2, deW, tWqkv, tWo, tW1, tW2, W_out, w_bf);
    transpose_kernel<<<(B_*T_*V_*C_ + 255) / 256, 256, 0, stream>>>(pose, p_bf);
    // y = p @ W_pose^T
    mfma_linear<128, 32, 0, false, true, true><<<dim3(RT_, 2), 256, 0, stream>>>(
        p_bf, w_bf + oWpose, nullptr, y, y_bf);

    for (int i = 0; i < 2; ++i) {
        // ---- graph encoder ----
        mfma_linear<256, 32, 0, false, true, false><<<dim3(RT_, 4), 256, 0, stream>>>(
            p_bf, w_bf + oWemb + i * 8192, nullptr, e, nullptr);
        bias2_kernel<<<BT_, 256, 0, stream>>>(
            e, prelu_a + i, W_bias + (size_t)i * H_ * HD_, biasbuf);
        mfma_linear<384, 128, 0, true, true, false><<<dim3(RT_, 6), 256, 0, stream>>>(
            y_bf, w_bf + oGqkv + i * 49152, gbqkv + (size_t)i * 384, qkvf, nullptr);
        attn_graph_kernel<<<dim3(BT_, H_), 384, 0, stream>>>(qkvf, biasbuf, attn_bf);
        mfma_linear<128, 128, 0, true, true, false><<<dim3(RT_, 2), 256, 0, stream>>>(
            attn_bf, w_bf + oGwo + i * 16384, gbo + (size_t)i * D_, tmp, nullptr);
        ln_add_kernel<true, true><<<ROWS, 64, 0, stream>>>(
            y, tmp, gln1g + (size_t)i * D_, gln1b + (size_t)i * D_, y1, y1_bf);
        mfma_linear<256, 128, 1, true, false, true><<<dim3(RT_, 4), 256, 0, stream>>>(
            y1_bf, w_bf + oGw1 + i * 32768, gb1 + (size_t)i * HD_, nullptr, hid_bf);
        mfma_linear<128, 256, 0, true, true, false><<<dim3(RT_, 2), 256, 0, stream>>>(
            hid_bf, w_bf + oGw2 + i * 32768, gb2 + (size_t)i * D_, tmp, nullptr);
        ln_add_kernel<false, true><<<ROWS, 64, 0, stream>>>(
            y1, tmp, gln2g + (size_t)i * D_, gln2b + (size_t)i * D_, nullptr, t2_bf);
        mfma_linear<128, 128, 0, true, true, false><<<dim3(RT_, 2), 256, 0, stream>>>(
            t2_bf, w_bf + oDe + i * 16384, deb + (size_t)i * D_, tmp, nullptr);
        add_pe_kernel<<<(ROWS * D_ + 255) / 256, 256, 0, stream>>>(tmp, y, y_bf);  // y = mem

        // ---- temporal encoder ----
        mfma_linear<384, 128, 0, true, true, false><<<dim3(RT_, 6), 256, 0, stream>>>(
            y_bf, w_bf + oTqkv + i * 49152, tbqkv + (size_t)i * 384, qkvf, nullptr);
        attn_temporal_kernel<<<dim3(BV_, H_), 256, 0, stream>>>(qkvf, attn_bf);
        mfma_linear<128, 128, 0, true, true, false><<<dim3(RT_, 2), 256, 0, stream>>>(
            attn_bf, w_bf + oTwo + i * 16384, tbo + (size_t)i * D_, tmp, nullptr);
        ln_add_kernel<true, true><<<ROWS, 64, 0, stream>>>(
            y, tmp, tln1g + (size_t)i * D_, tln1b + (size_t)i * D_, y1, y1_bf);
        mfma_linear<256, 128, 1, true, false, true><<<dim3(RT_, 4), 256, 0, stream>>>(
            y1_bf, w_bf + oTw1 + i * 32768, tb1 + (size_t)i * HD_, nullptr, hid_bf);
        mfma_linear<128, 256, 0, true, true, false><<<dim3(RT_, 2), 256, 0, stream>>>(
            hid_bf, w_bf + oTw2 + i * 32768, tb2 + (size_t)i * D_, tmp, nullptr);
        ln_add_kernel<true, false><<<ROWS, 64, 0, stream>>>(
            y1, tmp, tln2g + (size_t)i * D_, tln2b + (size_t)i * D_, t2, nullptr);
        add_kernel<<<(ROWS * D_ + 255) / 256, 256, 0, stream>>>(y, y_bf, t2);   // y += mem-resid
    }

    // final projection + LeakyReLU
    mfma_linear<64, 128, 2, false, true, false><<<dim3(RT_, 1), 256, 0, stream>>>(
        y_bf, w_bf + oWout, nullptr, outf, nullptr);
}

// Round 9
// 773.162 us; speedup vs baseline: 10.1135x; 1.0512x over previous
//
#include <hip/hip_runtime.h>
#include <hip/hip_bf16.h>
#include <math.h>

// Shapes (fixed by the problem)
#define B_  16
#define C_  32
#define T_  62
#define V_  19
#define D_  128
#define HD_ 256
#define H_  8
#define DH_ 16            // D_/H_
#define ROWS 18848        // B*T*V == B*V*T  (= 16*1178)
#define RT_  1178         // ROWS/16 row-tiles
#define BT_ 992           // B*T
#define BV_ 304           // B*V

typedef __attribute__((ext_vector_type(8))) short short8v;   // 8 bf16 (4 VGPRs)
typedef __attribute__((ext_vector_type(4))) float f32x4;

struct alignas(8) bf4 { __hip_bfloat16 x, y, z, w; };

// ---------------------------------------------------------------------------
// pose [B,C,T,V] -> p_bf [B,T,V,C] (bf16; only consumed by bf16 GEMMs)
__global__ void transpose_kernel(const float* __restrict__ pose, __hip_bfloat16* __restrict__ p_bf) {
    int idx = blockIdx.x * 256 + threadIdx.x;
    if (idx >= B_ * T_ * V_ * C_) return;
    int c = idx & 31;
    int rest = idx >> 5;          // b*T*V + t*V + v
    int v = rest % V_;
    int rest2 = rest / V_;
    int t = rest2 % T_;
    int b = rest2 / T_;
    p_bf[idx] = __float2bfloat16(pose[((size_t)((b * C_ + c) * T_ + t)) * V_ + v]);
}

// ---------------------------------------------------------------------------
// Convert all weight matrices to bf16 into one contiguous buffer (one launch).
__global__ void wconv_kernel(
        const float* s0, const float* s1, const float* s2, const float* s3,
        const float* s4, const float* s5, const float* s6, const float* s7,
        const float* s8, const float* s9, const float* s10, const float* s11,
        __hip_bfloat16* __restrict__ dst) {
    int idx = blockIdx.x * 256 + threadIdx.x;
    if (idx >= 585728) return;
    const float* s; int base;
    if      (idx <   4096) { s = s0;  base = 0;      }
    else if (idx <  20480) { s = s1;  base = 4096;   }
    else if (idx < 118784) { s = s2;  base = 20480;  }
    else if (idx < 151552) { s = s3;  base = 118784; }
    else if (idx < 217088) { s = s4;  base = 151552; }
    else if (idx < 282624) { s = s5;  base = 217088; }
    else if (idx < 315392) { s = s6;  base = 282624; }
    else if (idx < 413696) { s = s7;  base = 315392; }
    else if (idx < 446464) { s = s8;  base = 413696; }
    else if (idx < 512000) { s = s9;  base = 446464; }
    else if (idx < 577536) { s = s10; base = 512000; }
    else                   { s = s11; base = 577536; }
    dst[idx] = __float2bfloat16(s[idx - base]);
}

// ---------------------------------------------------------------------------
// MFMA linear: out[r,n] = epi(bias[n] + sum_k A[r,k]*W[n,k]), A/W bf16, acc fp32.
// One wave per 16x16 tile; grid = (RT_, N/64).
// EPI: 0 none, 1 relu, 2 leaky(0.01), 3 add positional encoding (t = row%62, col=oc)
template<int N, int K, int EPI, bool HASBIAS, bool O32, bool O16>
__global__ __launch_bounds__(256) void mfma_linear(
        const __hip_bfloat16* __restrict__ A, const __hip_bfloat16* __restrict__ W,
        const float* __restrict__ bias, float* __restrict__ out32,
        __hip_bfloat16* __restrict__ out16) {
    int wave = threadIdx.x >> 6;
    int lane = threadIdx.x & 63;
    int rt = blockIdx.x;
    int nt = blockIdx.y * 4 + wave;
    int r0 = rt * 16, n0 = nt * 16;
    int rl = lane & 15;
    int kk = (lane >> 4) * 8;
    const short* Ab = (const short*)A + (size_t)(r0 + rl) * K + kk;
    const short* Wb = (const short*)W + (size_t)(n0 + rl) * K + kk;
    f32x4 acc = {0.f, 0.f, 0.f, 0.f};
    #pragma unroll
    for (int kb = 0; kb < K / 32; ++kb) {
        short8v a = *reinterpret_cast<const short8v*>(Ab + kb * 32);
        short8v b = *reinterpret_cast<const short8v*>(Wb + kb * 32);
        acc = __builtin_amdgcn_mfma_f32_16x16x32_bf16(a, b, acc, 0, 0, 0);
    }
    int oc = n0 + rl;
    int or0 = r0 + (lane >> 4) * 4;
    float bv = HASBIAS ? bias[oc] : 0.f;
    float freq = 0.f;
    if (EPI == 3) freq = expf(-(float)(oc & ~1) * (9.210340371976184f / 128.f));
    #pragma unroll
    for (int j = 0; j < 4; ++j) {
        float v = acc[j] + bv;
        if (EPI == 1) v = fmaxf(v, 0.f);
        if (EPI == 2) v = v >= 0.f ? v : 0.01f * v;
        if (EPI == 3) {
            int t = (or0 + j) % T_;
            float ang = (float)t * freq;
            v += (oc & 1) ? cosf(ang) : sinf(ang);
        }
        if (O32) out32[(size_t)(or0 + j) * N + oc] = v;
        if (O16) out16[(size_t)(or0 + j) * N + oc] = __float2bfloat16(v);
    }
}

// ---------------------------------------------------------------------------
// bias2: using e = p @ Wemb^T  [BT*V, 256] (linearity of the pairwise diff):
// bias[bt,i,j,g] = scale * sum_hh Wbias[g,hh] * prelu(e[bt,j,hh] - e[bt,i,hh])
__global__ __launch_bounds__(256) void bias2_kernel(
        const float* __restrict__ e, const float* __restrict__ prelu_a,
        const float* __restrict__ Wbias, float* __restrict__ bias) {
    int bt = blockIdx.x;
    __shared__ float es[V_ * 257];
    int tid = threadIdx.x;
    for (int idx = tid; idx < V_ * HD_; idx += 256) {
        int v = idx >> 8, hh = idx & 255;
        es[v * 257 + hh] = e[((size_t)(bt * V_ + v)) * HD_ + hh];
    }
    __syncthreads();
    const float a = prelu_a[0];
    const float scale = 0.35355339059327373f;   // 1/sqrt(8)
    for (int pair = tid; pair < V_ * V_; pair += 256) {
        int i = pair / V_, j = pair - i * V_;
        const float* ei = es + i * 257;
        const float* ej = es + j * 257;
        float ag[H_] = {0.f, 0.f, 0.f, 0.f, 0.f, 0.f, 0.f, 0.f};
        #pragma unroll 4
        for (int hh = 0; hh < HD_; ++hh) {
            float d = ej[hh] - ei[hh];
            float hv = d >= 0.f ? d : a * d;
            #pragma unroll
            for (int g = 0; g < H_; ++g) ag[g] += Wbias[g * HD_ + hh] * hv;
        }
        float* bout = bias + ((size_t)bt * (V_ * V_) + pair) * H_;
        #pragma unroll
        for (int g = 0; g < H_; ++g) bout[g] = ag[g] * scale;
    }
}

// ---------------------------------------------------------------------------
// Graph attention: per (bt, h). LDS-staged q/k/v, scores 19x19 in LDS. bf16 out.
__global__ __launch_bounds__(384) void attn_graph_kernel(
        const float* __restrict__ qkv, const float* __restrict__ bias,
        __hip_bfloat16* __restrict__ out) {
    int bt = blockIdx.x;
    int h = blockIdx.y;
    __shared__ float q_lds[V_][20];
    __shared__ float k_lds[V_][20];
    __shared__ float v_lds[V_][20];
    __shared__ float sm[V_][20];
    int tid = threadIdx.x;
    for (int idx = tid; idx < V_ * 4 * 3; idx += 384) {
        int mat = idx / (V_ * 4);
        int rem = idx - mat * (V_ * 4);
        int row = rem >> 2, part = rem & 3;
        float4 val = *reinterpret_cast<const float4*>(
            qkv + ((size_t)(bt * V_ + row)) * 384 + mat * 128 + h * DH_ + part * 4);
        float* dst = (mat == 0 ? q_lds[row] : (mat == 1 ? k_lds[row] : v_lds[row])) + part * 4;
        *reinterpret_cast<float4*>(dst) = val;
    }
    __syncthreads();
    if (tid < V_ * V_) {
        int i = tid / V_, j = tid - i * V_;
        float acc = 0.f;
        #pragma unroll
        for (int c = 0; c < 4; ++c) {
            float4 qv = *reinterpret_cast<const float4*>(&q_lds[i][4 * c]);
            float4 kv = *reinterpret_cast<const float4*>(&k_lds[j][4 * c]);
            acc += qv.x * kv.x + qv.y * kv.y + qv.z * kv.z + qv.w * kv.w;
        }
        sm[i][j] = acc * 0.25f + bias[((size_t)(bt * V_ + i) * V_ + j) * H_ + h];
    }
    __syncthreads();
    if (tid < V_) {
        float m = -1e30f;
        for (int j = 0; j < V_; ++j) m = fmaxf(m, sm[tid][j]);
        float sum = 0.f;
        for (int j = 0; j < V_; ++j) { float e = __expf(sm[tid][j] - m); sm[tid][j] = e; sum += e; }
        float inv = 1.f / sum;
        for (int j = 0; j < V_; ++j) sm[tid][j] *= inv;
    }
    __syncthreads();
    if (tid < V_ * DH_) {
        int i = tid / DH_, d = tid - i * DH_;
        float o = 0.f;
        #pragma unroll 4
        for (int j = 0; j < V_; ++j) o += sm[i][j] * v_lds[j][d];
        out[((size_t)(bt * V_ + i)) * D_ + h * DH_ + d] = __float2bfloat16(o);
    }
}

// ---------------------------------------------------------------------------
// Temporal attention: per (b, h). LDS-staged q/k/v; softmax in registers.
// Lane jt owns j = 4*jj + jt (strided): the 4 lanes of a row read CONSECUTIVE
// k rows (stride 20 floats -> disjoint bank spans, conflict-free).
__global__ __launch_bounds__(256) void attn_temporal_kernel(
        const float* __restrict__ qkv, __hip_bfloat16* __restrict__ out) {
    int b = blockIdx.x;
    int h = blockIdx.y;
    __shared__ float q_lds[T_][20];
    __shared__ float k_lds[T_][20];
    __shared__ float v_lds[T_][20];
    __shared__ float sm[T_][68];
    int tid = threadIdx.x;
    for (int idx = tid; idx < T_ * 4 * 3; idx += 256) {
        int mat = idx / (T_ * 4);
        int rem = idx - mat * (T_ * 4);
        int row = rem >> 2, part = rem & 3;
        float4 val = *reinterpret_cast<const float4*>(
            qkv + ((size_t)(b * T_ + row)) * 384 + mat * 128 + h * DH_ + part * 4);
        float* dst = (mat == 0 ? q_lds[row] : (mat == 1 ? k_lds[row] : v_lds[row])) + part * 4;
        *reinterpret_cast<float4*>(dst) = val;
    }
    __syncthreads();
    if (tid < T_ * 4) {
        int i = tid >> 2, jt = tid & 3;
        float qreg[16];
        #pragma unroll
        for (int c = 0; c < 4; ++c) {
            float4 qv = *reinterpret_cast<const float4*>(&q_lds[i][4 * c]);
            qreg[4 * c + 0] = qv.x * 0.25f;
            qreg[4 * c + 1] = qv.y * 0.25f;
            qreg[4 * c + 2] = qv.z * 0.25f;
            qreg[4 * c + 3] = qv.w * 0.25f;
        }
        float s[16];
        #pragma unroll
        for (int jj = 0; jj < 16; ++jj) {
            int j = jj * 4 + jt;
            float acc = -1e30f;
            if (j < T_) {
                acc = 0.f;
                const float* kr = k_lds[j];
                #pragma unroll
                for (int c = 0; c < 4; ++c) {
                    float4 kv = *reinterpret_cast<const float4*>(&kr[4 * c]);
                    acc += qreg[4*c+0] * kv.x + qreg[4*c+1] * kv.y
                         + qreg[4*c+2] * kv.z + qreg[4*c+3] * kv.w;
                }
            }
            s[jj] = acc;
        }
        float m = -1e30f;
        #pragma unroll
        for (int jj = 0; jj < 16; ++jj) m = fmaxf(m, s[jj]);
        m = fmaxf(m, __shfl_xor(m, 1, 64));
        m = fmaxf(m, __shfl_xor(m, 2, 64));
        float sum = 0.f;
        #pragma unroll
        for (int jj = 0; jj < 16; ++jj) {
            int j = jj * 4 + jt;
            float e = (j < T_) ? __expf(s[jj] - m) : 0.f;
            s[jj] = e;
            sum += e;
        }
        sum += __shfl_xor(sum, 1, 64);
        sum += __shfl_xor(sum, 2, 64);
        float inv = 1.f / sum;
        #pragma unroll
        for (int jj = 0; jj < 16; ++jj) {
            int j = jj * 4 + jt;
            if (j < T_) sm[i][j] = s[jj] * inv;
        }
    }
    __syncthreads();
    if (tid < T_ * 4) {
        int i = tid >> 2, dg = tid & 3;
        float4 o = {0.f, 0.f, 0.f, 0.f};
        for (int j = 0; j < T_; ++j) {
            float pp = sm[i][j];
            const float4 vv = *reinterpret_cast<const float4*>(&v_lds[j][4 * dg]);
            o.x += pp * vv.x; o.y += pp * vv.y; o.z += pp * vv.z; o.w += pp * vv.w;
        }
        bf4 ov = { __float2bfloat16(o.x), __float2bfloat16(o.y),
                   __float2bfloat16(o.z), __float2bfloat16(o.w) };
        *reinterpret_cast<bf4*>(out + ((size_t)(b * T_ + i)) * D_ + h * DH_ + 4 * dg) = ov;
    }
}

// ---------------------------------------------------------------------------
// out = LN(x + r) * g + b; optionally fp32 and/or bf16 outputs.
template<bool O32, bool O16>
__global__ __launch_bounds__(64) void ln_add_kernel(
        const float* __restrict__ x, const float* __restrict__ r,
        const float* __restrict__ g, const float* __restrict__ b,
        float* __restrict__ o32, __hip_bfloat16* __restrict__ o16) {
    int row = blockIdx.x;
    int lane = threadIdx.x;
    const float* xr = x + (size_t)row * D_;
    const float* rr = r + (size_t)row * D_;
    float v0 = xr[lane] + rr[lane];
    float v1 = xr[lane + 64] + rr[lane + 64];
    float s = v0 + v1, sq = v0 * v0 + v1 * v1;
    #pragma unroll
    for (int off = 32; off > 0; off >>= 1) {
        s += __shfl_xor(s, off, 64);
        sq += __shfl_xor(sq, off, 64);
    }
    float mean = s * (1.f / 128.f);
    float var = sq * (1.f / 128.f) - mean * mean;
    float rstd = rsqrtf(var + 1e-5f);
    float a0 = (v0 - mean) * rstd * g[lane]      + b[lane];
    float a1 = (v1 - mean) * rstd * g[lane + 64] + b[lane + 64];
    if (O32) {
        float* o = o32 + (size_t)row * D_;
        o[lane] = a0; o[lane + 64] = a1;
    }
    if (O16) {
        __hip_bfloat16* o = o16 + (size_t)row * D_;
        o[lane] = __float2bfloat16(a0); o[lane + 64] = __float2bfloat16(a1);
    }
}

// y += x  (fp32 + bf16 copies)
__global__ void add_kernel(float* __restrict__ y, __hip_bfloat16* __restrict__ y_bf,
                           const float* __restrict__ x) {
    int idx = blockIdx.x * 256 + threadIdx.x;
    if (idx >= ROWS * D_) return;
    float v = y[idx] + x[idx];
    y[idx] = v;
    y_bf[idx] = __float2bfloat16(v);
}

// ---------------------------------------------------------------------------
extern "C" void kernel_launch(void* const* d_in, const int* in_sizes, int n_in,
                              void* d_out, int out_size, void* d_ws, size_t ws_size,
                              hipStream_t stream) {
    const float* pose    = (const float*)d_in[0];
    const float* W_pose  = (const float*)d_in[1];
    const float* W_emb   = (const float*)d_in[2];
    const float* prelu_a = (const float*)d_in[3];
    const float* W_bias  = (const float*)d_in[4];
    const float* gWqkv   = (const float*)d_in[5];
    const float* gbqkv   = (const float*)d_in[6];
    const float* gWo     = (const float*)d_in[7];
    const float* gbo     = (const float*)d_in[8];
    const float* gln1g   = (const float*)d_in[9];
    const float* gln1b   = (const float*)d_in[10];
    const float* gW1     = (const float*)d_in[11];
    const float* gb1     = (const float*)d_in[12];
    const float* gW2     = (const float*)d_in[13];
    const float* gb2     = (const float*)d_in[14];
    const float* gln2g   = (const float*)d_in[15];
    const float* gln2b   = (const float*)d_in[16];
    const float* deW     = (const float*)d_in[17];
    const float* deb     = (const float*)d_in[18];
    const float* tWqkv   = (const float*)d_in[19];
    const float* tbqkv   = (const float*)d_in[20];
    const float* tWo     = (const float*)d_in[21];
    const float* tbo     = (const float*)d_in[22];
    const float* tln1g   = (const float*)d_in[23];
    const float* tln1b   = (const float*)d_in[24];
    const float* tW1     = (const float*)d_in[25];
    const float* tb1     = (const float*)d_in[26];
    const float* tW2     = (const float*)d_in[27];
    const float* tb2     = (const float*)d_in[28];
    const float* tln2g   = (const float*)d_in[29];
    const float* tln2b   = (const float*)d_in[30];
    const float* W_out   = (const float*)d_in[31];

    float* ws = (float*)d_ws;
    // workspace layout (float-slot offsets) — identical to round 7 (passed)
    __hip_bfloat16* p_bf   = (__hip_bfloat16*)(ws + 0);          // ROWS*32 bf16
    float*          y      = ws + 301568;                        // ROWS*128 f32
    __hip_bfloat16* y_bf   = (__hip_bfloat16*)(ws + 2714112);    // ROWS*128 bf16
    float*          biasbuf= ws + 3920384;                       // BT*361*8 f32
    float*          big    = ws + 6785280;                       // 7,237,632 f32
    float*          e      = big;                                // ROWS*256 f32 (pre-qkv)
    float*          qkvf   = big;                                // ROWS*384 f32
    float*          tmp    = big;                                // ROWS*128 f32 (post-attn)
    __hip_bfloat16* hid_bf = (__hip_bfloat16*)(big + 2412544);   // ROWS*256 bf16
    float*          y1     = big + 4825088;                      // ROWS*128 f32
    __hip_bfloat16* attn_bf= (__hip_bfloat16*)(ws + 14022912);   // ROWS*128 bf16
    float*          t2     = ws + 15229184;                      // ROWS*128 f32 region
    __hip_bfloat16* y1_bf  = (__hip_bfloat16*)t2;                // (phase-disjoint with t2)
    __hip_bfloat16* t2_bf  = (__hip_bfloat16*)t2;
    __hip_bfloat16* w_bf   = (__hip_bfloat16*)(ws + 17641728);   // 585,728 bf16 weights
    float*          outf   = (float*)d_out;

    // bf16 weight offsets (elems)
    const int oWpose = 0, oWemb = 4096, oGqkv = 20480, oGwo = 118784, oGw1 = 151552,
              oGw2 = 217088, oDe = 282624, oTqkv = 315392, oTwo = 413696,
              oTw1 = 446464, oTw2 = 512000, oWout = 577536;

    wconv_kernel<<<(585728 + 255) / 256, 256, 0, stream>>>(
        W_pose, W_emb, gWqkv, gWo, gW1, gW2, deW, tWqkv, tWo, tW1, tW2, W_out, w_bf);
    transpose_kernel<<<(B_*T_*V_*C_ + 255) / 256, 256, 0, stream>>>(pose, p_bf);
    // y = p @ W_pose^T
    mfma_linear<128, 32, 0, false, true, true><<<dim3(RT_, 2), 256, 0, stream>>>(
        p_bf, w_bf + oWpose, nullptr, y, y_bf);

    for (int i = 0; i < 2; ++i) {
        // ---- graph encoder ----
        mfma_linear<256, 32, 0, false, true, false><<<dim3(RT_, 4), 256, 0, stream>>>(
            p_bf, w_bf + oWemb + i * 8192, nullptr, e, nullptr);
        bias2_kernel<<<BT_, 256, 0, stream>>>(
            e, prelu_a + i, W_bias + (size_t)i * H_ * HD_, biasbuf);
        mfma_linear<384, 128, 0, true, true, false><<<dim3(RT_, 6), 256, 0, stream>>>(
            y_bf, w_bf + oGqkv + i * 49152, gbqkv + (size_t)i * 384, qkvf, nullptr);
        attn_graph_kernel<<<dim3(BT_, H_), 384, 0, stream>>>(qkvf, biasbuf, attn_bf);
        mfma_linear<128, 128, 0, true, true, false><<<dim3(RT_, 2), 256, 0, stream>>>(
            attn_bf, w_bf + oGwo + i * 16384, gbo + (size_t)i * D_, tmp, nullptr);
        ln_add_kernel<true, true><<<ROWS, 64, 0, stream>>>(
            y, tmp, gln1g + (size_t)i * D_, gln1b + (size_t)i * D_, y1, y1_bf);
        mfma_linear<256, 128, 1, true, false, true><<<dim3(RT_, 4), 256, 0, stream>>>(
            y1_bf, w_bf + oGw1 + i * 32768, gb1 + (size_t)i * HD_, nullptr, hid_bf);
        mfma_linear<128, 256, 0, true, true, false><<<dim3(RT_, 2), 256, 0, stream>>>(
            hid_bf, w_bf + oGw2 + i * 32768, gb2 + (size_t)i * D_, tmp, nullptr);
        ln_add_kernel<false, true><<<ROWS, 64, 0, stream>>>(
            y1, tmp, gln2g + (size_t)i * D_, gln2b + (size_t)i * D_, nullptr, t2_bf);
        // y = de@t2 + deb + PE   (fused positional-encoding epilogue)
        mfma_linear<128, 128, 3, true, true, true><<<dim3(RT_, 2), 256, 0, stream>>>(
            t2_bf, w_bf + oDe + i * 16384, deb + (size_t)i * D_, y, y_bf);

        // ---- temporal encoder ----
        mfma_linear<384, 128, 0, true, true, false><<<dim3(RT_, 6), 256, 0, stream>>>(
            y_bf, w_bf + oTqkv + i * 49152, tbqkv + (size_t)i * 384, qkvf, nullptr);
        attn_temporal_kernel<<<dim3(BV_, H_), 256, 0, stream>>>(qkvf, attn_bf);
        mfma_linear<128, 128, 0, true, true, false><<<dim3(RT_, 2), 256, 0, stream>>>(
            attn_bf, w_bf + oTwo + i * 16384, tbo + (size_t)i * D_, tmp, nullptr);
        ln_add_kernel<true, true><<<ROWS, 64, 0, stream>>>(
            y, tmp, tln1g + (size_t)i * D_, tln1b + (size_t)i * D_, y1, y1_bf);
        mfma_linear<256, 128, 1, true, false, true><<<dim3(RT_, 4), 256, 0, stream>>>(
            y1_bf, w_bf + oTw1 + i * 32768, tb1 + (size_t)i * HD_, nullptr, hid_bf);
        mfma_linear<128, 256, 0, true, true, false><<<dim3(RT_, 2), 256, 0, stream>>>(
            hid_bf, w_bf + oTw2 + i * 32768, tb2 + (size_t)i * D_, tmp, nullptr);
        ln_add_kernel<true, false><<<ROWS, 64, 0, stream>>>(
            y1, tmp, tln2g + (size_t)i * D_, tln2b + (size_t)i * D_, t2, nullptr);
        add_kernel<<<(ROWS * D_ + 255) / 256, 256, 0, stream>>>(y, y_bf, t2);   // y += mem-resid
    }

    // final projection + LeakyReLU
    mfma_linear<64, 128, 2, false, true, false><<<dim3(RT_, 1), 256, 0, stream>>>(
        y_bf, w_bf + oWout, nullptr, outf, nullptr);
}